// Round 4
// baseline (499.524 us; speedup 1.0000x reference)
//
#include <hip/hip_runtime.h>
#include <hip/hip_bf16.h>

// B=8, S=1024, H=1024, NH=16, DH=64. Inputs fp32 (proven r1/r4), output f32
// (proven r4), mask dtype sniffed 4-way. All GEMMs pure bf16 after a convert
// pass; V projection writes per-head-TRANSPOSED Vbt so attention reads V in
// MFMA fragment order directly from global.
// r2: attn blockIdx XCD-grouping — all 16 qt-tiles of one (b,h) on the same
// XCD; K/V fetched once per XCD, L2-hot (FETCH 139MB->25MB, confirmed).
// r3: occupancy 21->31% changed nothing -> bottleneck = per-CU LDS unit
// (~74% occupied: staging + 32 b128 frag reads + P + shfl per wave-iter).
// r4: K and V MFMA fragments loaded DIRECTLY from global (L2-hot) at the
// fragment addresses; no K/V LDS staging, no per-iteration barriers at all.
// LDS keeps only the per-wave P strip + maskf (20.5KB); 4 blocks/CU.
#define Bn 8
#define Sn 1024
#define Hn 1024
#define NHn 16
#define DHn 64
#define Mn (Bn * Sn)

typedef unsigned short u16;
typedef short bf16x8 __attribute__((ext_vector_type(8)));
typedef unsigned short u16x4 __attribute__((ext_vector_type(4)));
typedef float f32x4 __attribute__((ext_vector_type(4)));

__device__ __forceinline__ u16 f2bf(float x) {
  union { __hip_bfloat16 h; u16 u; } cv;
  cv.h = __float2bfloat16(x);
  return cv.u;
}

__device__ __forceinline__ void async_ld16(void* lds, const void* g) {
  __builtin_amdgcn_global_load_lds(
      (const __attribute__((address_space(1))) void*)g,
      (__attribute__((address_space(3))) void*)lds, 16, 0, 0);
}

// ---------------------------------------------------------------------------
// Mask dtype sniffer: flags[1] = 0:i32 1:i8 2:bf16 3:f32 (f32 before bf16).
// Deterministic every call (graph-safe).
// ---------------------------------------------------------------------------
__global__ __launch_bounds__(256) void sniff_k(const void* __restrict__ mask,
                                               int* __restrict__ flags) {
  __shared__ int viol;
  if (threadIdx.x == 0) viol = 0;
  __syncthreads();
  const unsigned* mw = (const unsigned*)mask;
  int vb = 0;
#pragma unroll
  for (int j = 0; j < 8; ++j) {
    unsigned v = mw[threadIdx.x * 8 + j];          // first 8192B valid for all dtypes
    if (v > 1u) vb |= 1;
    if ((v & 0xFEFEFEFEu) != 0u) vb |= 2;
    if (!(v == 0u || v == 0x3F800000u)) vb |= 4;
    unsigned h0 = v & 0xFFFFu, h1 = v >> 16;
    if (!((h0 == 0u || h0 == 0x3F80u) && (h1 == 0u || h1 == 0x3F80u))) vb |= 8;
  }
  if (vb) atomicOr(&viol, vb);
  __syncthreads();
  if (threadIdx.x == 0) {
    int mt;
    if (!(viol & 1))      mt = 0;
    else if (!(viol & 2)) mt = 1;
    else if (!(viol & 4)) mt = 3;
    else if (!(viol & 8)) mt = 2;
    else                  mt = 0;
    flags[1] = mt;
  }
}

// fp32 -> bf16: three equal tensors of 8388608 elems, one thread = 8 elems.
__global__ __launch_bounds__(256) void convert3(
    const float* __restrict__ a, const float* __restrict__ b,
    const float* __restrict__ c, u16* __restrict__ da,
    u16* __restrict__ db, u16* __restrict__ dc) {
  const int seg = blockIdx.x >> 12;                 // 4096 blocks per tensor
  const int bid = blockIdx.x & 4095;
  const float* s = seg == 0 ? a : seg == 1 ? b : c;
  u16* d        = seg == 0 ? da : seg == 1 ? db : dc;
  const int i = (bid * 256 + threadIdx.x) * 8;
  f32x4 lo = *(const f32x4*)(s + i);
  f32x4 hi = *(const f32x4*)(s + i + 4);
  bf16x8 o;
#pragma unroll
  for (int j = 0; j < 4; ++j) { o[j] = (short)f2bf(lo[j]); o[4 + j] = (short)f2bf(hi[j]); }
  *(bf16x8*)(d + i) = o;
}

// fp32 -> bf16: four 1048576-elem weights.
__global__ __launch_bounds__(256) void convertW(
    const float* __restrict__ a, const float* __restrict__ b,
    const float* __restrict__ c, const float* __restrict__ e,
    u16* __restrict__ da, u16* __restrict__ db,
    u16* __restrict__ dc, u16* __restrict__ de) {
  const int seg = blockIdx.x >> 9;                  // 512 blocks per tensor
  const int bid = blockIdx.x & 511;
  const float* s = seg == 0 ? a : seg == 1 ? b : seg == 2 ? c : e;
  u16* d        = seg == 0 ? da : seg == 1 ? db : seg == 2 ? dc : de;
  const int i = (bid * 256 + threadIdx.x) * 8;
  f32x4 lo = *(const f32x4*)(s + i);
  f32x4 hi = *(const f32x4*)(s + i + 4);
  bf16x8 o;
#pragma unroll
  for (int j = 0; j < 4; ++j) { o[j] = (short)f2bf(lo[j]); o[4 + j] = (short)f2bf(hi[j]); }
  *(bf16x8*)(d + i) = o;
}

// ---------------------------------------------------------------------------
// O = (X[8192,1024] @ W[1024,1024]^T + bias)*scale, bf16 in, fp32 accum.
// 128x128 tile, BK=32, global_load_lds width=16 (m97 structure).
// OMODE 0: bf16 row-major. 1: f32 row-major. 2: bf16 per-head transposed
// Vbt[(b*1024+col)*1024 + s] with packed b64 stores (V projection).
// ---------------------------------------------------------------------------
template <int OMODE>
__global__ __launch_bounds__(256) void gemm_bt(
    const u16* __restrict__ X, const u16* __restrict__ W,
    const float* __restrict__ bias, void* __restrict__ O, float scale)
{
  __shared__ __attribute__((aligned(16))) u16 As[128 * 32];
  __shared__ __attribute__((aligned(16))) u16 Bs[128 * 32];
  const int tid  = threadIdx.x;
  const int wave = tid >> 6;
  const int lane = tid & 63;
  const int ln   = lane & 15;
  const int quad = lane >> 4;
  const int m0 = blockIdx.x * 128;
  const int n0 = blockIdx.y * 128;
  const int wm = (wave & 1) * 64;
  const int wn = (wave >> 1) * 64;
  const int r0 = tid >> 2;          // staging row 0..63 (and +64)
  const int oc = (tid & 3) * 8;     // 16B column chunk
  char* A0 = (char*)As + wave * 1024;        // dest = base + lane*16 (HW rule)
  char* A1 = (char*)As + 4096 + wave * 1024;
  char* B0 = (char*)Bs + wave * 1024;
  char* B1 = (char*)Bs + 4096 + wave * 1024;

  f32x4 acc[4][4] = {};

  for (int k0 = 0; k0 < 1024; k0 += 32) {
    async_ld16(A0, X + (size_t)(m0 + r0) * 1024 + k0 + oc);
    async_ld16(A1, X + (size_t)(m0 + 64 + r0) * 1024 + k0 + oc);
    async_ld16(B0, W + (size_t)(n0 + r0) * 1024 + k0 + oc);
    async_ld16(B1, W + (size_t)(n0 + 64 + r0) * 1024 + k0 + oc);
    __syncthreads();
    bf16x8 af[4], bf[4];
#pragma unroll
    for (int t = 0; t < 4; ++t)
      af[t] = *(const bf16x8*)&As[(wm + t * 16 + ln) * 32 + quad * 8];
#pragma unroll
    for (int t = 0; t < 4; ++t)
      bf[t] = *(const bf16x8*)&Bs[(wn + t * 16 + ln) * 32 + quad * 8];
#pragma unroll
    for (int i = 0; i < 4; ++i)
#pragma unroll
      for (int j = 0; j < 4; ++j)
        acc[i][j] = __builtin_amdgcn_mfma_f32_16x16x32_bf16(af[i], bf[j], acc[i][j], 0, 0, 0);
    __syncthreads();
  }

  // C/D: col = lane&15 (+16j), row = quad*4 + r
  if (OMODE == 2) {
    const int bb = m0 >> 10;          // batch (tile never crosses batches)
    const int sb = m0 & 1023;
#pragma unroll
    for (int j = 0; j < 4; ++j) {
      const int col = n0 + wn + j * 16 + ln;
      const float bv = bias[col];
#pragma unroll
      for (int i = 0; i < 4; ++i) {
        const int sl = sb + wm + i * 16 + quad * 4;
        u16x4 pk;
#pragma unroll
        for (int r = 0; r < 4; ++r) pk[r] = f2bf((acc[i][j][r] + bv) * scale);
        *(u16x4*)&((u16*)O)[((size_t)(bb * 1024 + col)) * 1024 + sl] = pk;
      }
    }
  } else {
#pragma unroll
    for (int j = 0; j < 4; ++j) {
      const int col = n0 + wn + j * 16 + ln;
      const float bv = bias[col];
#pragma unroll
      for (int i = 0; i < 4; ++i) {
        const int rowb = m0 + wm + i * 16 + quad * 4;
#pragma unroll
        for (int r = 0; r < 4; ++r) {
          const float val = (acc[i][j][r] + bv) * scale;
          const size_t idx = (size_t)(rowb + r) * 1024 + col;
          if (OMODE == 1) ((float*)O)[idx] = val;
          else            ((u16*)O)[idx]   = f2bf(val);
        }
      }
    }
  }
}

// ---------------------------------------------------------------------------
// Flash attention v2: block = (b,h,64-row Q tile), 4 waves x 16 Q-rows,
// KV-tile 128 (8 iterations). r4: K and V MFMA B-operand fragments are
// 16B-aligned per-lane global loads at exactly the fragment addresses:
//   K frag: (b*S + kv0 + t*16 + ln)*H + h*64 + quad*8 (+32 for k-half 1)
//   V frag: (b*S + h*64 + dt*16 + ln)*S + kv0 + c*32 + quad*8   (Vbt layout)
// Both are L2-hot (r2 XCD grouping). No K/V LDS staging, no barriers in the
// KV loop — waves run fully decoupled. LDS: per-wave P strip + maskf only.
// ---------------------------------------------------------------------------
__global__ __launch_bounds__(256, 4) void attn(
    const u16* __restrict__ Qb, const u16* __restrict__ Kb,
    const u16* __restrict__ Vbt, const void* __restrict__ mask,
    const int* __restrict__ flags, u16* __restrict__ Ctx)
{
  __shared__ __attribute__((aligned(16))) u16 Pl[4][16 * 128]; // per-wave, swizzled
  __shared__ __attribute__((aligned(16))) float maskf[Sn];

  const int tid  = threadIdx.x;
  const int wave = tid >> 6;
  const int lane = tid & 63;
  const int ln   = lane & 15;
  const int quad = lane >> 4;
  // XCD-grouping decode: bx = x + 8*(qt + 16*grp), bh = grp*8 + x
  const int bx  = blockIdx.x;
  const int x   = bx & 7;
  const int qt  = (bx >> 3) & 15;
  const int grp = bx >> 7;
  const int bh  = grp * 8 + x;
  const int b   = bh >> 4;
  const int h   = bh & 15;

  const int mt = flags[1];
  for (int i = tid; i < Sn; i += 256) {
    const int idx = b * Sn + i;
    int nz;
    if (mt == 0)      nz = ((const int*)mask)[idx] != 0;
    else if (mt == 1) nz = ((const signed char*)mask)[idx] != 0;
    else if (mt == 2) nz = ((const u16*)mask)[idx] != 0;
    else              nz = ((const unsigned*)mask)[idx] != 0;
    maskf[i] = nz ? -1e9f : 0.0f;
  }
  __syncthreads();   // maskf ready; only barrier in the kernel

  // Q fragments (A-operand: m=lane&15, k=quad*8+j); Q pre-scaled by 1/8
  const size_t qoff = (size_t)(b * Sn + qt * 64 + wave * 16 + ln) * Hn + h * DHn;
  bf16x8 qf0 = *(const bf16x8*)&Qb[qoff + quad * 8];
  bf16x8 qf1 = *(const bf16x8*)&Qb[qoff + 32 + quad * 8];

  float mrun[4], lrun[4];
#pragma unroll
  for (int r = 0; r < 4; ++r) { mrun[r] = -INFINITY; lrun[r] = 0.0f; }
  f32x4 acc[4] = {};

  char* pw = (char*)Pl[wave];
  const int rsw = (ln & 7) << 4;           // P read-side swizzle (row = ln)

  // fragment-layout global bases (per-lane)
  const u16* kbase = Kb  + (size_t)(b * Sn + ln) * Hn + h * DHn + quad * 8;
  const u16* vbase = Vbt + (size_t)(b * Sn + h * DHn + ln) * Sn + quad * 8;

  for (int t8 = 0; t8 < 8; ++t8) {
    const int kv0 = t8 * 128;

    // S = Q K^T, K fragments straight from global (L2-hot)
    f32x4 sc[8];
#pragma unroll
    for (int t = 0; t < 8; ++t) {
      const u16* kp = kbase + (size_t)(kv0 + t * 16) * Hn;
      bf16x8 kf0 = *(const bf16x8*)(kp);
      bf16x8 kf1 = *(const bf16x8*)(kp + 32);
      f32x4 z = {};
      z = __builtin_amdgcn_mfma_f32_16x16x32_bf16(qf0, kf0, z, 0, 0, 0);
      z = __builtin_amdgcn_mfma_f32_16x16x32_bf16(qf1, kf1, z, 0, 0, 0);
      sc[t] = z;
    }
    float mf[8];
#pragma unroll
    for (int t = 0; t < 8; ++t) mf[t] = maskf[kv0 + t * 16 + ln];
#pragma unroll
    for (int t = 0; t < 8; ++t)
#pragma unroll
      for (int r = 0; r < 4; ++r) sc[t][r] += mf[t];

    // online softmax per Q-row (row r lives in this quad's 16 lanes)
    float al[4], mx[4];
#pragma unroll
    for (int r = 0; r < 4; ++r) {
      float v = sc[0][r];
#pragma unroll
      for (int t = 1; t < 8; ++t) v = fmaxf(v, sc[t][r]);
      v = fmaxf(v, __shfl_xor(v, 1));
      v = fmaxf(v, __shfl_xor(v, 2));
      v = fmaxf(v, __shfl_xor(v, 4));
      v = fmaxf(v, __shfl_xor(v, 8));
      const float mnew = fmaxf(mrun[r], v);
      al[r] = __expf(mrun[r] - mnew);
      mrun[r] = mnew;
      mx[r] = mnew;
    }
#pragma unroll
    for (int r = 0; r < 4; ++r) {
      float s = 0.0f;
#pragma unroll
      for (int t = 0; t < 8; ++t) {
        const float p = __expf(sc[t][r] - mx[r]);
        sc[t][r] = p;
        s += p;
      }
      s += __shfl_xor(s, 1);
      s += __shfl_xor(s, 2);
      s += __shfl_xor(s, 4);
      s += __shfl_xor(s, 8);
      lrun[r] = lrun[r] * al[r] + s;
    }
    // P: C-layout -> per-wave LDS strip -> A-layout. Same-wave write->read:
    // LDS ops issue in order within a wave; compiler inserts the lgkmcnt.
#pragma unroll
    for (int t = 0; t < 8; ++t)
#pragma unroll
      for (int r = 0; r < 4; ++r) {
        const int prow = quad * 4 + r;
        *(u16*)(pw + ((prow * 256 + (t * 16 + ln) * 2) ^ ((prow & 7) << 4))) =
            f2bf(sc[t][r]);
      }
#pragma unroll
    for (int dt = 0; dt < 4; ++dt)
#pragma unroll
      for (int r = 0; r < 4; ++r) acc[dt][r] *= al[r];
    bf16x8 pa[4];
#pragma unroll
    for (int c = 0; c < 4; ++c)
      pa[c] = *(const bf16x8*)(pw + ((ln * 256 + c * 64 + quad * 16) ^ rsw));
    // PV: V fragments straight from global (Vbt, L2-hot)
#pragma unroll
    for (int dt = 0; dt < 4; ++dt) {
      const u16* vp = vbase + (size_t)(dt * 16) * Sn + kv0;
#pragma unroll
      for (int c = 0; c < 4; ++c) {
        bf16x8 vb = *(const bf16x8*)(vp + c * 32);
        acc[dt] = __builtin_amdgcn_mfma_f32_16x16x32_bf16(pa[c], vb, acc[dt], 0, 0, 0);
      }
    }
  }

#pragma unroll
  for (int dt = 0; dt < 4; ++dt)
#pragma unroll
    for (int r = 0; r < 4; ++r) {
      const int s = qt * 64 + wave * 16 + quad * 4 + r;
      Ctx[(size_t)(b * Sn + s) * Hn + h * DHn + dt * 16 + ln] = f2bf(acc[dt][r] / lrun[r]);
    }
}

extern "C" void kernel_launch(void* const* d_in, const int* in_sizes, int n_in,
                              void* d_out, int out_size, void* d_ws, size_t ws_size,
                              hipStream_t stream) {
  const float* v    = (const float*)d_in[0];
  const float* k    = (const float*)d_in[1];
  const float* q    = (const float*)d_in[2];
  const void*  mask = d_in[3];
  const float* Wq   = (const float*)d_in[4];
  const float* bq   = (const float*)d_in[5];
  const float* Wk   = (const float*)d_in[6];
  const float* bk   = (const float*)d_in[7];
  const float* Wv   = (const float*)d_in[8];
  const float* bv   = (const float*)d_in[9];
  const float* Wm   = (const float*)d_in[10];
  const float* bm   = (const float*)d_in[11];

  // ws layout (56MB + 8B, extents proven safe in round 2/3):
  char* ws = (char*)d_ws;
  u16* qc  = (u16*)(ws);                  // 16MB, consumed by Q-proj -> reused as Vbt
  u16* kc  = (u16*)(ws + (16u << 20));    // 16MB, consumed by K-proj -> reused as Cx
  u16* vc  = (u16*)(ws + (32u << 20));    // 16MB
  u16* Wqc = (u16*)(ws + (48u << 20));    // 2MB each
  u16* Wkc = Wqc + (1u << 20);
  u16* Wvc = Wkc + (1u << 20);
  u16* Wmc = Wvc + (1u << 20);
  int* flags = (int*)(ws + (56u << 20));
  u16* Vbt = qc;
  u16* Cx  = kc;
  u16* Qb  = (u16*)d_out;                 // d_out (32MB f32) hosts Qb+Kb bf16
  u16* Kb  = Qb + (size_t)Mn * Hn;

  sniff_k<<<1, 256, 0, stream>>>(mask, flags);
  convert3<<<3 * 4096, 256, 0, stream>>>(q, k, v, qc, kc, vc);
  convertW<<<4 * 512, 256, 0, stream>>>(Wq, Wk, Wv, Wm, Wqc, Wkc, Wvc, Wmc);

  dim3 grid(Mn / 128, Hn / 128), blk(256);
  gemm_bt<0><<<grid, blk, 0, stream>>>(qc, Wqc, bq, Qb, 0.125f);
  gemm_bt<0><<<grid, blk, 0, stream>>>(kc, Wkc, bk, Kb, 1.0f);
  gemm_bt<2><<<grid, blk, 0, stream>>>(vc, Wvc, bv, Vbt, 1.0f);   // over qc
  attn<<<dim3(Bn * NHn * (Sn / 64)), blk, 0, stream>>>(Qb, Kb, Vbt, mask, flags, Cx); // over kc
  gemm_bt<1><<<grid, blk, 0, stream>>>(Cx, Wmc, bm, d_out, 1.0f);
}

// Round 5
// 364.450 us; speedup vs baseline: 1.3706x; 1.3706x over previous
//
#include <hip/hip_runtime.h>
#include <hip/hip_bf16.h>

// B=8, S=1024, H=1024, NH=16, DH=64. Inputs fp32 (proven r1/r4), output f32
// (proven r4), mask dtype sniffed 4-way. All GEMMs pure bf16 after a convert
// pass; V projection writes per-head-TRANSPOSED Vbt so attention stages V
// coalesced with no scatter.
// r2: attn blockIdx XCD-grouping — K/V L2-hot (FETCH 139MB->25MB, confirmed).
// r3: unpadded XOR-swizzled LDS, 53248B -> 3 blocks/CU; P-barrier dropped.
// r4 (REVERTED): direct-global K/V fragments -> 16 lines/instr, TCP-bound 2x.
// r5: softmax reductions via DPP (quad_perm xor1/xor2 + row_ror:4/8) on the
// VALU instead of __shfl_xor's ds_bpermute on the LDS pipe — removes 32 LDS
// ops + 4-deep ~30cyc serial chains per wave-iter from the bottleneck pipe.
#define Bn 8
#define Sn 1024
#define Hn 1024
#define NHn 16
#define DHn 64
#define Mn (Bn * Sn)

typedef unsigned short u16;
typedef short bf16x8 __attribute__((ext_vector_type(8)));
typedef unsigned short u16x4 __attribute__((ext_vector_type(4)));
typedef float f32x4 __attribute__((ext_vector_type(4)));

__device__ __forceinline__ u16 f2bf(float x) {
  union { __hip_bfloat16 h; u16 u; } cv;
  cv.h = __float2bfloat16(x);
  return cv.u;
}

__device__ __forceinline__ void async_ld16(void* lds, const void* g) {
  __builtin_amdgcn_global_load_lds(
      (const __attribute__((address_space(1))) void*)g,
      (__attribute__((address_space(3))) void*)lds, 16, 0, 0);
}

// DPP cross-lane within each 16-lane row (VALU pipe, not LDS).
// ctrl: 0xB1 = quad_perm xor1, 0x4E = quad_perm xor2,
//       0x124 = row_ror:4, 0x128 = row_ror:8.
template <int CTRL>
__device__ __forceinline__ float dpp_mov(float v) {
  union { float f; int i; } a, b;
  a.f = v;
  b.i = __builtin_amdgcn_mov_dpp(a.i, CTRL, 0xF, 0xF, 1);
  return b.f;
}
// full 16-lane reduce: xor1, xor2 make quads uniform; ror4 merges adjacent
// quads; ror8 merges opposite pairs -> every lane holds the full reduction.
__device__ __forceinline__ float row16_max(float v) {
  v = fmaxf(v, dpp_mov<0xB1>(v));
  v = fmaxf(v, dpp_mov<0x4E>(v));
  v = fmaxf(v, dpp_mov<0x124>(v));
  v = fmaxf(v, dpp_mov<0x128>(v));
  return v;
}
__device__ __forceinline__ float row16_sum(float v) {
  v += dpp_mov<0xB1>(v);
  v += dpp_mov<0x4E>(v);
  v += dpp_mov<0x124>(v);
  v += dpp_mov<0x128>(v);
  return v;
}

// ---------------------------------------------------------------------------
// Mask dtype sniffer: flags[1] = 0:i32 1:i8 2:bf16 3:f32 (f32 before bf16).
// Deterministic every call (graph-safe).
// ---------------------------------------------------------------------------
__global__ __launch_bounds__(256) void sniff_k(const void* __restrict__ mask,
                                               int* __restrict__ flags) {
  __shared__ int viol;
  if (threadIdx.x == 0) viol = 0;
  __syncthreads();
  const unsigned* mw = (const unsigned*)mask;
  int vb = 0;
#pragma unroll
  for (int j = 0; j < 8; ++j) {
    unsigned v = mw[threadIdx.x * 8 + j];          // first 8192B valid for all dtypes
    if (v > 1u) vb |= 1;
    if ((v & 0xFEFEFEFEu) != 0u) vb |= 2;
    if (!(v == 0u || v == 0x3F800000u)) vb |= 4;
    unsigned h0 = v & 0xFFFFu, h1 = v >> 16;
    if (!((h0 == 0u || h0 == 0x3F80u) && (h1 == 0u || h1 == 0x3F80u))) vb |= 8;
  }
  if (vb) atomicOr(&viol, vb);
  __syncthreads();
  if (threadIdx.x == 0) {
    int mt;
    if (!(viol & 1))      mt = 0;
    else if (!(viol & 2)) mt = 1;
    else if (!(viol & 4)) mt = 3;
    else if (!(viol & 8)) mt = 2;
    else                  mt = 0;
    flags[1] = mt;
  }
}

// fp32 -> bf16: three equal tensors of 8388608 elems, one thread = 8 elems.
__global__ __launch_bounds__(256) void convert3(
    const float* __restrict__ a, const float* __restrict__ b,
    const float* __restrict__ c, u16* __restrict__ da,
    u16* __restrict__ db, u16* __restrict__ dc) {
  const int seg = blockIdx.x >> 12;                 // 4096 blocks per tensor
  const int bid = blockIdx.x & 4095;
  const float* s = seg == 0 ? a : seg == 1 ? b : c;
  u16* d        = seg == 0 ? da : seg == 1 ? db : dc;
  const int i = (bid * 256 + threadIdx.x) * 8;
  f32x4 lo = *(const f32x4*)(s + i);
  f32x4 hi = *(const f32x4*)(s + i + 4);
  bf16x8 o;
#pragma unroll
  for (int j = 0; j < 4; ++j) { o[j] = (short)f2bf(lo[j]); o[4 + j] = (short)f2bf(hi[j]); }
  *(bf16x8*)(d + i) = o;
}

// fp32 -> bf16: four 1048576-elem weights.
__global__ __launch_bounds__(256) void convertW(
    const float* __restrict__ a, const float* __restrict__ b,
    const float* __restrict__ c, const float* __restrict__ e,
    u16* __restrict__ da, u16* __restrict__ db,
    u16* __restrict__ dc, u16* __restrict__ de) {
  const int seg = blockIdx.x >> 9;                  // 512 blocks per tensor
  const int bid = blockIdx.x & 511;
  const float* s = seg == 0 ? a : seg == 1 ? b : seg == 2 ? c : e;
  u16* d        = seg == 0 ? da : seg == 1 ? db : seg == 2 ? dc : de;
  const int i = (bid * 256 + threadIdx.x) * 8;
  f32x4 lo = *(const f32x4*)(s + i);
  f32x4 hi = *(const f32x4*)(s + i + 4);
  bf16x8 o;
#pragma unroll
  for (int j = 0; j < 4; ++j) { o[j] = (short)f2bf(lo[j]); o[4 + j] = (short)f2bf(hi[j]); }
  *(bf16x8*)(d + i) = o;
}

// ---------------------------------------------------------------------------
// O = (X[8192,1024] @ W[1024,1024]^T + bias)*scale, bf16 in, fp32 accum.
// 128x128 tile, BK=32, global_load_lds width=16 (m97 structure).
// OMODE 0: bf16 row-major. 1: f32 row-major. 2: bf16 per-head transposed
// Vbt[(b*1024+col)*1024 + s] with packed b64 stores (V projection).
// ---------------------------------------------------------------------------
template <int OMODE>
__global__ __launch_bounds__(256) void gemm_bt(
    const u16* __restrict__ X, const u16* __restrict__ W,
    const float* __restrict__ bias, void* __restrict__ O, float scale)
{
  __shared__ __attribute__((aligned(16))) u16 As[128 * 32];
  __shared__ __attribute__((aligned(16))) u16 Bs[128 * 32];
  const int tid  = threadIdx.x;
  const int wave = tid >> 6;
  const int lane = tid & 63;
  const int ln   = lane & 15;
  const int quad = lane >> 4;
  const int m0 = blockIdx.x * 128;
  const int n0 = blockIdx.y * 128;
  const int wm = (wave & 1) * 64;
  const int wn = (wave >> 1) * 64;
  const int r0 = tid >> 2;          // staging row 0..63 (and +64)
  const int oc = (tid & 3) * 8;     // 16B column chunk
  char* A0 = (char*)As + wave * 1024;        // dest = base + lane*16 (HW rule)
  char* A1 = (char*)As + 4096 + wave * 1024;
  char* B0 = (char*)Bs + wave * 1024;
  char* B1 = (char*)Bs + 4096 + wave * 1024;

  f32x4 acc[4][4] = {};

  for (int k0 = 0; k0 < 1024; k0 += 32) {
    async_ld16(A0, X + (size_t)(m0 + r0) * 1024 + k0 + oc);
    async_ld16(A1, X + (size_t)(m0 + 64 + r0) * 1024 + k0 + oc);
    async_ld16(B0, W + (size_t)(n0 + r0) * 1024 + k0 + oc);
    async_ld16(B1, W + (size_t)(n0 + 64 + r0) * 1024 + k0 + oc);
    __syncthreads();
    bf16x8 af[4], bf[4];
#pragma unroll
    for (int t = 0; t < 4; ++t)
      af[t] = *(const bf16x8*)&As[(wm + t * 16 + ln) * 32 + quad * 8];
#pragma unroll
    for (int t = 0; t < 4; ++t)
      bf[t] = *(const bf16x8*)&Bs[(wn + t * 16 + ln) * 32 + quad * 8];
#pragma unroll
    for (int i = 0; i < 4; ++i)
#pragma unroll
      for (int j = 0; j < 4; ++j)
        acc[i][j] = __builtin_amdgcn_mfma_f32_16x16x32_bf16(af[i], bf[j], acc[i][j], 0, 0, 0);
    __syncthreads();
  }

  // C/D: col = lane&15 (+16j), row = quad*4 + r
  if (OMODE == 2) {
    const int bb = m0 >> 10;          // batch (tile never crosses batches)
    const int sb = m0 & 1023;
#pragma unroll
    for (int j = 0; j < 4; ++j) {
      const int col = n0 + wn + j * 16 + ln;
      const float bv = bias[col];
#pragma unroll
      for (int i = 0; i < 4; ++i) {
        const int sl = sb + wm + i * 16 + quad * 4;
        u16x4 pk;
#pragma unroll
        for (int r = 0; r < 4; ++r) pk[r] = f2bf((acc[i][j][r] + bv) * scale);
        *(u16x4*)&((u16*)O)[((size_t)(bb * 1024 + col)) * 1024 + sl] = pk;
      }
    }
  } else {
#pragma unroll
    for (int j = 0; j < 4; ++j) {
      const int col = n0 + wn + j * 16 + ln;
      const float bv = bias[col];
#pragma unroll
      for (int i = 0; i < 4; ++i) {
        const int rowb = m0 + wm + i * 16 + quad * 4;
#pragma unroll
        for (int r = 0; r < 4; ++r) {
          const float val = (acc[i][j][r] + bv) * scale;
          const size_t idx = (size_t)(rowb + r) * 1024 + col;
          if (OMODE == 1) ((float*)O)[idx] = val;
          else            ((u16*)O)[idx]   = f2bf(val);
        }
      }
    }
  }
}

// ---------------------------------------------------------------------------
// Flash attention v2: block = (b,h,64-row Q tile), 4 waves x 16 Q-rows,
// KV-tile 128 (8 iterations). K/V staged via LDS, V from pre-transposed Vbt.
// r2 XCD swizzle; r3 unpadded XOR-swizzled LDS (53248B, 3 blocks/CU), no
// P-barrier. r5: softmax reduces on VALU via DPP (see row16_max/row16_sum)
// instead of ds_bpermute — LDS pipe keeps only staging + frag reads + P.
// ---------------------------------------------------------------------------
__global__ __launch_bounds__(256, 3) void attn(
    const u16* __restrict__ Qb, const u16* __restrict__ Kb,
    const u16* __restrict__ Vbt, const void* __restrict__ mask,
    const int* __restrict__ flags, u16* __restrict__ Ctx)
{
  __shared__ __attribute__((aligned(16))) u16 Ks[128 * 64];    // [kv][d], swizzled
  __shared__ __attribute__((aligned(16))) u16 Vt[64 * 128];    // [d][kv], swizzled
  __shared__ __attribute__((aligned(16))) u16 Pl[4][16 * 128]; // per-wave, swizzled
  __shared__ __attribute__((aligned(16))) float maskf[Sn];

  const int tid  = threadIdx.x;
  const int wave = tid >> 6;
  const int lane = tid & 63;
  const int ln   = lane & 15;
  const int quad = lane >> 4;
  // XCD-grouping decode: bx = x + 8*(qt + 16*grp), bh = grp*8 + x
  const int bx  = blockIdx.x;
  const int x   = bx & 7;
  const int qt  = (bx >> 3) & 15;
  const int grp = bx >> 7;
  const int bh  = grp * 8 + x;
  const int b   = bh >> 4;
  const int h   = bh & 15;

  const int mt = flags[1];
  for (int i = tid; i < Sn; i += 256) {
    const int idx = b * Sn + i;
    int nz;
    if (mt == 0)      nz = ((const int*)mask)[idx] != 0;
    else if (mt == 1) nz = ((const signed char*)mask)[idx] != 0;
    else if (mt == 2) nz = ((const u16*)mask)[idx] != 0;
    else              nz = ((const unsigned*)mask)[idx] != 0;
    maskf[i] = nz ? -1e9f : 0.0f;
  }

  // Q fragments (A-operand: m=lane&15, k=quad*8+j); Q pre-scaled by 1/8
  const size_t qoff = (size_t)(b * Sn + qt * 64 + wave * 16 + ln) * Hn + h * DHn;
  bf16x8 qf0 = *(const bf16x8*)&Qb[qoff + quad * 8];
  bf16x8 qf1 = *(const bf16x8*)&Qb[qoff + 32 + quad * 8];

  float mrun[4], lrun[4];
#pragma unroll
  for (int r = 0; r < 4; ++r) { mrun[r] = -INFINITY; lrun[r] = 0.0f; }
  f32x4 acc[4] = {};

  const int kr = tid >> 1, kh = tid & 1;   // K stage: 2 threads/row (64B each)
  const int vd = tid >> 2, vs = tid & 3;   // V stage: 4 threads/row (64B each)
  char* pw  = (char*)Pl[wave];
  char* KsB = (char*)Ks;
  char* VtB = (char*)Vt;

  const int kwb = kr * 128 + kh * 64;      // K write byte base (unswizzled)
  const int ksw = (kr & 7) << 4;
  const int vwb = vd * 256 + vs * 64;      // V write byte base
  const int vsw = (vd & 7) << 4;
  const int rsw = (ln & 7) << 4;           // read-side swizzle (row&7 == ln&7)

  for (int t8 = 0; t8 < 8; ++t8) {
    const int kv0 = t8 * 128;
    __syncthreads();  // previous Ks/Vt fully consumed
    {
      const u16* g = &Kb[(size_t)(b * Sn + kv0 + kr) * Hn + h * DHn + kh * 32];
#pragma unroll
      for (int j = 0; j < 4; ++j)
        *(bf16x8*)(KsB + ((kwb + j * 16) ^ ksw)) = *(const bf16x8*)(g + j * 8);
    }
    {
      const u16* g = &Vbt[(size_t)(b * Sn + h * DHn + vd) * Sn + kv0 + vs * 32];
#pragma unroll
      for (int j = 0; j < 4; ++j)
        *(bf16x8*)(VtB + ((vwb + j * 16) ^ vsw)) = *(const bf16x8*)(g + j * 8);
    }
    __syncthreads();

    // S = Q K^T from LDS (B-operand: n=lane&15 -> kv row, k=quad*8+j -> d)
    f32x4 sc[8];
#pragma unroll
    for (int t = 0; t < 8; ++t) {
      const int rb = (t * 16 + ln) * 128;
      bf16x8 kf0 = *(const bf16x8*)(KsB + ((rb + quad * 16) ^ rsw));
      bf16x8 kf1 = *(const bf16x8*)(KsB + ((rb + 64 + quad * 16) ^ rsw));
      f32x4 z = {};
      z = __builtin_amdgcn_mfma_f32_16x16x32_bf16(qf0, kf0, z, 0, 0, 0);
      z = __builtin_amdgcn_mfma_f32_16x16x32_bf16(qf1, kf1, z, 0, 0, 0);
      sc[t] = z;
    }
    float mf[8];
#pragma unroll
    for (int t = 0; t < 8; ++t) mf[t] = maskf[kv0 + t * 16 + ln];
#pragma unroll
    for (int t = 0; t < 8; ++t)
#pragma unroll
      for (int r = 0; r < 4; ++r) sc[t][r] += mf[t];

    // online softmax per Q-row (row r lives in this quad's 16 lanes);
    // reductions across the 16 lanes on the VALU via DPP.
    float al[4], mx[4];
#pragma unroll
    for (int r = 0; r < 4; ++r) {
      float v = sc[0][r];
#pragma unroll
      for (int t = 1; t < 8; ++t) v = fmaxf(v, sc[t][r]);
      v = row16_max(v);
      const float mnew = fmaxf(mrun[r], v);
      al[r] = __expf(mrun[r] - mnew);
      mrun[r] = mnew;
      mx[r] = mnew;
    }
#pragma unroll
    for (int r = 0; r < 4; ++r) {
      float s = 0.0f;
#pragma unroll
      for (int t = 0; t < 8; ++t) {
        const float p = __expf(sc[t][r] - mx[r]);
        sc[t][r] = p;
        s += p;
      }
      s = row16_sum(s);
      lrun[r] = lrun[r] * al[r] + s;
    }
    // P: C-layout -> per-wave LDS strip -> A-layout. Same-wave write->read:
    // LDS ops issue in order within a wave; compiler inserts the lgkmcnt.
#pragma unroll
    for (int t = 0; t < 8; ++t)
#pragma unroll
      for (int r = 0; r < 4; ++r) {
        const int prow = quad * 4 + r;
        *(u16*)(pw + ((prow * 256 + (t * 16 + ln) * 2) ^ ((prow & 7) << 4))) =
            f2bf(sc[t][r]);
      }
#pragma unroll
    for (int dt = 0; dt < 4; ++dt)
#pragma unroll
      for (int r = 0; r < 4; ++r) acc[dt][r] *= al[r];
    bf16x8 pa[4];
#pragma unroll
    for (int c = 0; c < 4; ++c)
      pa[c] = *(const bf16x8*)(pw + ((ln * 256 + c * 64 + quad * 16) ^ rsw));
#pragma unroll
    for (int dt = 0; dt < 4; ++dt) {
      const int vrb = (dt * 16 + ln) * 256;
#pragma unroll
      for (int c = 0; c < 4; ++c) {
        bf16x8 vb = *(const bf16x8*)(VtB + ((vrb + c * 64 + quad * 16) ^ rsw));
        acc[dt] = __builtin_amdgcn_mfma_f32_16x16x32_bf16(pa[c], vb, acc[dt], 0, 0, 0);
      }
    }
  }

#pragma unroll
  for (int dt = 0; dt < 4; ++dt)
#pragma unroll
    for (int r = 0; r < 4; ++r) {
      const int s = qt * 64 + wave * 16 + quad * 4 + r;
      Ctx[(size_t)(b * Sn + s) * Hn + h * DHn + dt * 16 + ln] = f2bf(acc[dt][r] / lrun[r]);
    }
}

extern "C" void kernel_launch(void* const* d_in, const int* in_sizes, int n_in,
                              void* d_out, int out_size, void* d_ws, size_t ws_size,
                              hipStream_t stream) {
  const float* v    = (const float*)d_in[0];
  const float* k    = (const float*)d_in[1];
  const float* q    = (const float*)d_in[2];
  const void*  mask = d_in[3];
  const float* Wq   = (const float*)d_in[4];
  const float* bq   = (const float*)d_in[5];
  const float* Wk   = (const float*)d_in[6];
  const float* bk   = (const float*)d_in[7];
  const float* Wv   = (const float*)d_in[8];
  const float* bv   = (const float*)d_in[9];
  const float* Wm   = (const float*)d_in[10];
  const float* bm   = (const float*)d_in[11];

  // ws layout (56MB + 8B, extents proven safe in round 2/3):
  char* ws = (char*)d_ws;
  u16* qc  = (u16*)(ws);                  // 16MB, consumed by Q-proj -> reused as Vbt
  u16* kc  = (u16*)(ws + (16u << 20));    // 16MB, consumed by K-proj -> reused as Cx
  u16* vc  = (u16*)(ws + (32u << 20));    // 16MB
  u16* Wqc = (u16*)(ws + (48u << 20));    // 2MB each
  u16* Wkc = Wqc + (1u << 20);
  u16* Wvc = Wkc + (1u << 20);
  u16* Wmc = Wvc + (1u << 20);
  int* flags = (int*)(ws + (56u << 20));
  u16* Vbt = qc;
  u16* Cx  = kc;
  u16* Qb  = (u16*)d_out;                 // d_out (32MB f32) hosts Qb+Kb bf16
  u16* Kb  = Qb + (size_t)Mn * Hn;

  sniff_k<<<1, 256, 0, stream>>>(mask, flags);
  convert3<<<3 * 4096, 256, 0, stream>>>(q, k, v, qc, kc, vc);
  convertW<<<4 * 512, 256, 0, stream>>>(Wq, Wk, Wv, Wm, Wqc, Wkc, Wvc, Wmc);

  dim3 grid(Mn / 128, Hn / 128), blk(256);
  gemm_bt<0><<<grid, blk, 0, stream>>>(qc, Wqc, bq, Qb, 0.125f);
  gemm_bt<0><<<grid, blk, 0, stream>>>(kc, Wkc, bk, Kb, 1.0f);
  gemm_bt<2><<<grid, blk, 0, stream>>>(vc, Wvc, bv, Vbt, 1.0f);   // over qc
  attn<<<dim3(Bn * NHn * (Sn / 64)), blk, 0, stream>>>(Qb, Kb, Vbt, mask, flags, Cx); // over kc
  gemm_bt<1><<<grid, blk, 0, stream>>>(Cx, Wmc, bm, d_out, 1.0f);
}

// Round 6
// 354.515 us; speedup vs baseline: 1.4090x; 1.0280x over previous
//
#include <hip/hip_runtime.h>
#include <hip/hip_bf16.h>

// B=8, S=1024, H=1024, NH=16, DH=64. Inputs fp32 (proven r1/r4), output f32
// (proven r4), mask dtype sniffed 4-way. All GEMMs pure bf16 after a convert
// pass; V projection writes per-head-TRANSPOSED Vbt so attention stages V
// coalesced with no scatter.
// r2: attn blockIdx XCD-grouping — K/V L2-hot (FETCH 139MB->25MB, confirmed).
// r3: unpadded XOR-swizzled LDS, 53248B -> 3 blocks/CU; P-barrier dropped.
// r5: softmax reductions via DPP on VALU (attn 129.5 -> 105.7us, confirmed).
// r6: GEMM side (was ~220us of 364us, LDS-read-bound at 2 blocks/CU):
//   - Q-proj + K-proj fused into one dispatch (blockIdx.z) -> 4 blocks/CU.
//   - BK 32->64: half the barriers per GEMM; LDS 32KB.
//   - gll-compatible XOR swizzle (pre-swizzled SOURCE + swizzled READ,
//     linear dest per rule #21): frag reads spread 32 banks, 2 lanes/bank.
#define Bn 8
#define Sn 1024
#define Hn 1024
#define NHn 16
#define DHn 64
#define Mn (Bn * Sn)

typedef unsigned short u16;
typedef short bf16x8 __attribute__((ext_vector_type(8)));
typedef unsigned short u16x4 __attribute__((ext_vector_type(4)));
typedef float f32x4 __attribute__((ext_vector_type(4)));

__device__ __forceinline__ u16 f2bf(float x) {
  union { __hip_bfloat16 h; u16 u; } cv;
  cv.h = __float2bfloat16(x);
  return cv.u;
}

__device__ __forceinline__ void async_ld16(void* lds, const void* g) {
  __builtin_amdgcn_global_load_lds(
      (const __attribute__((address_space(1))) void*)g,
      (__attribute__((address_space(3))) void*)lds, 16, 0, 0);
}

// DPP cross-lane within each 16-lane row (VALU pipe, not LDS).
template <int CTRL>
__device__ __forceinline__ float dpp_mov(float v) {
  union { float f; int i; } a, b;
  a.f = v;
  b.i = __builtin_amdgcn_mov_dpp(a.i, CTRL, 0xF, 0xF, 1);
  return b.f;
}
__device__ __forceinline__ float row16_max(float v) {
  v = fmaxf(v, dpp_mov<0xB1>(v));
  v = fmaxf(v, dpp_mov<0x4E>(v));
  v = fmaxf(v, dpp_mov<0x124>(v));
  v = fmaxf(v, dpp_mov<0x128>(v));
  return v;
}
__device__ __forceinline__ float row16_sum(float v) {
  v += dpp_mov<0xB1>(v);
  v += dpp_mov<0x4E>(v);
  v += dpp_mov<0x124>(v);
  v += dpp_mov<0x128>(v);
  return v;
}

// ---------------------------------------------------------------------------
// Mask dtype sniffer: flags[1] = 0:i32 1:i8 2:bf16 3:f32 (f32 before bf16).
// ---------------------------------------------------------------------------
__global__ __launch_bounds__(256) void sniff_k(const void* __restrict__ mask,
                                               int* __restrict__ flags) {
  __shared__ int viol;
  if (threadIdx.x == 0) viol = 0;
  __syncthreads();
  const unsigned* mw = (const unsigned*)mask;
  int vb = 0;
#pragma unroll
  for (int j = 0; j < 8; ++j) {
    unsigned v = mw[threadIdx.x * 8 + j];          // first 8192B valid for all dtypes
    if (v > 1u) vb |= 1;
    if ((v & 0xFEFEFEFEu) != 0u) vb |= 2;
    if (!(v == 0u || v == 0x3F800000u)) vb |= 4;
    unsigned h0 = v & 0xFFFFu, h1 = v >> 16;
    if (!((h0 == 0u || h0 == 0x3F80u) && (h1 == 0u || h1 == 0x3F80u))) vb |= 8;
  }
  if (vb) atomicOr(&viol, vb);
  __syncthreads();
  if (threadIdx.x == 0) {
    int mt;
    if (!(viol & 1))      mt = 0;
    else if (!(viol & 2)) mt = 1;
    else if (!(viol & 4)) mt = 3;
    else if (!(viol & 8)) mt = 2;
    else                  mt = 0;
    flags[1] = mt;
  }
}

// fp32 -> bf16: three equal tensors of 8388608 elems, one thread = 8 elems.
__global__ __launch_bounds__(256) void convert3(
    const float* __restrict__ a, const float* __restrict__ b,
    const float* __restrict__ c, u16* __restrict__ da,
    u16* __restrict__ db, u16* __restrict__ dc) {
  const int seg = blockIdx.x >> 12;                 // 4096 blocks per tensor
  const int bid = blockIdx.x & 4095;
  const float* s = seg == 0 ? a : seg == 1 ? b : c;
  u16* d        = seg == 0 ? da : seg == 1 ? db : dc;
  const int i = (bid * 256 + threadIdx.x) * 8;
  f32x4 lo = *(const f32x4*)(s + i);
  f32x4 hi = *(const f32x4*)(s + i + 4);
  bf16x8 o;
#pragma unroll
  for (int j = 0; j < 4; ++j) { o[j] = (short)f2bf(lo[j]); o[4 + j] = (short)f2bf(hi[j]); }
  *(bf16x8*)(d + i) = o;
}

// fp32 -> bf16: four 1048576-elem weights.
__global__ __launch_bounds__(256) void convertW(
    const float* __restrict__ a, const float* __restrict__ b,
    const float* __restrict__ c, const float* __restrict__ e,
    u16* __restrict__ da, u16* __restrict__ db,
    u16* __restrict__ dc, u16* __restrict__ de) {
  const int seg = blockIdx.x >> 9;                  // 512 blocks per tensor
  const int bid = blockIdx.x & 511;
  const float* s = seg == 0 ? a : seg == 1 ? b : seg == 2 ? c : e;
  u16* d        = seg == 0 ? da : seg == 1 ? db : seg == 2 ? dc : de;
  const int i = (bid * 256 + threadIdx.x) * 8;
  f32x4 lo = *(const f32x4*)(s + i);
  f32x4 hi = *(const f32x4*)(s + i + 4);
  bf16x8 o;
#pragma unroll
  for (int j = 0; j < 4; ++j) { o[j] = (short)f2bf(lo[j]); o[4 + j] = (short)f2bf(hi[j]); }
  *(bf16x8*)(d + i) = o;
}

// ---------------------------------------------------------------------------
// O = (X[8192,1024] @ W[1024,1024]^T + bias)*scale, bf16 in, fp32 accum.
// 128x128 tile, BK=64 (r6), global_load_lds width=16.
// Staging: op j covers rows j*32..+31; lane loads pre-swizzled global chunk
// ((l&7)^(row&7)) so LDS[row][c'] = X[row][c'^(row&7)]; frag reads XOR back
// -> conflict-free (32 banks, 2 lanes/bank). Two 32-wide k-halves per step.
// OMODE 0: bf16 row-major. 1: f32 row-major. 2: bf16 per-head transposed
// Vbt[(b*1024+col)*1024 + s] with packed b64 stores (V projection).
// ---------------------------------------------------------------------------
template <int OMODE>
__device__ __forceinline__ void gemm_core(
    u16* As, u16* Bs, const u16* __restrict__ X, const u16* __restrict__ W,
    const float* __restrict__ bias, void* __restrict__ O, float scale)
{
  const int tid  = threadIdx.x;
  const int wave = tid >> 6;
  const int lane = tid & 63;
  const int ln   = lane & 15;
  const int quad = lane >> 4;
  const int m0 = blockIdx.x * 128;
  const int n0 = blockIdx.y * 128;
  const int wm = (wave & 1) * 64;
  const int wn = (wave >> 1) * 64;
  const int r8 = tid >> 3;                       // staging row within 32-group ×4
  const int cg = ((tid & 7) ^ (r8 & 7)) * 8;     // pre-swizzled global col chunk
  char* Ad = (char*)As + wave * 1024;            // gll dest: wave-uniform + lane*16
  char* Bd = (char*)Bs + wave * 1024;
  const int rsw = ln & 7;                        // read-side row swizzle bits

  f32x4 acc[4][4] = {};

  for (int k0 = 0; k0 < 1024; k0 += 64) {
#pragma unroll
    for (int j = 0; j < 4; ++j) {
      async_ld16(Ad + j * 4096, X + (size_t)(m0 + j * 32 + r8) * 1024 + k0 + cg);
      async_ld16(Bd + j * 4096, W + (size_t)(n0 + j * 32 + r8) * 1024 + k0 + cg);
    }
    __syncthreads();
#pragma unroll
    for (int s = 0; s < 2; ++s) {
      const int co = ((s * 4 + quad) ^ rsw) * 16;   // swizzled 16B chunk offset
      bf16x8 af[4], bfr[4];
#pragma unroll
      for (int t = 0; t < 4; ++t)
        af[t] = *(const bf16x8*)((char*)As + (wm + t * 16 + ln) * 128 + co);
#pragma unroll
      for (int t = 0; t < 4; ++t)
        bfr[t] = *(const bf16x8*)((char*)Bs + (wn + t * 16 + ln) * 128 + co);
#pragma unroll
      for (int i = 0; i < 4; ++i)
#pragma unroll
        for (int j = 0; j < 4; ++j)
          acc[i][j] = __builtin_amdgcn_mfma_f32_16x16x32_bf16(af[i], bfr[j], acc[i][j], 0, 0, 0);
    }
    __syncthreads();
  }

  // C/D: col = lane&15 (+16j), row = quad*4 + r
  if (OMODE == 2) {
    const int bb = m0 >> 10;          // batch (tile never crosses batches)
    const int sb = m0 & 1023;
#pragma unroll
    for (int j = 0; j < 4; ++j) {
      const int col = n0 + wn + j * 16 + ln;
      const float bv = bias[col];
#pragma unroll
      for (int i = 0; i < 4; ++i) {
        const int sl = sb + wm + i * 16 + quad * 4;
        u16x4 pk;
#pragma unroll
        for (int r = 0; r < 4; ++r) pk[r] = f2bf((acc[i][j][r] + bv) * scale);
        *(u16x4*)&((u16*)O)[((size_t)(bb * 1024 + col)) * 1024 + sl] = pk;
      }
    }
  } else {
#pragma unroll
    for (int j = 0; j < 4; ++j) {
      const int col = n0 + wn + j * 16 + ln;
      const float bv = bias[col];
#pragma unroll
      for (int i = 0; i < 4; ++i) {
        const int rowb = m0 + wm + i * 16 + quad * 4;
#pragma unroll
        for (int r = 0; r < 4; ++r) {
          const float val = (acc[i][j][r] + bv) * scale;
          const size_t idx = (size_t)(rowb + r) * 1024 + col;
          if (OMODE == 1) ((float*)O)[idx] = val;
          else            ((u16*)O)[idx]   = f2bf(val);
        }
      }
    }
  }
}

template <int OMODE>
__global__ __launch_bounds__(256, 3) void gemm_bt(
    const u16* __restrict__ X, const u16* __restrict__ W,
    const float* __restrict__ bias, void* __restrict__ O, float scale)
{
  __shared__ __attribute__((aligned(16))) u16 As[128 * 64];
  __shared__ __attribute__((aligned(16))) u16 Bs[128 * 64];
  gemm_core<OMODE>(As, Bs, X, W, bias, O, scale);
}

// Fused Q-proj (z=0) + K-proj (z=1): independent inputs/outputs, doubles
// blocks/CU (4 resident) for the projection phase.
__global__ __launch_bounds__(256, 3) void gemm_qk(
    const u16* __restrict__ Xq, const u16* __restrict__ Wq,
    const float* __restrict__ bq, u16* __restrict__ Oq,
    const u16* __restrict__ Xk, const u16* __restrict__ Wk,
    const float* __restrict__ bk, u16* __restrict__ Ok)
{
  __shared__ __attribute__((aligned(16))) u16 As[128 * 64];
  __shared__ __attribute__((aligned(16))) u16 Bs[128 * 64];
  const int z = blockIdx.z;
  gemm_core<0>(As, Bs, z ? Xk : Xq, z ? Wk : Wq, z ? bk : bq,
               z ? (void*)Ok : (void*)Oq, z ? 1.0f : 0.125f);
}

// ---------------------------------------------------------------------------
// Flash attention v2 (r5 version, unchanged): block = (b,h,64-row Q tile),
// 4 waves x 16 Q-rows, KV-tile 128. XCD-grouped blockIdx; unpadded
// XOR-swizzled LDS (53248B, 3 blocks/CU); DPP softmax reductions on VALU.
// ---------------------------------------------------------------------------
__global__ __launch_bounds__(256, 3) void attn(
    const u16* __restrict__ Qb, const u16* __restrict__ Kb,
    const u16* __restrict__ Vbt, const void* __restrict__ mask,
    const int* __restrict__ flags, u16* __restrict__ Ctx)
{
  __shared__ __attribute__((aligned(16))) u16 Ks[128 * 64];    // [kv][d], swizzled
  __shared__ __attribute__((aligned(16))) u16 Vt[64 * 128];    // [d][kv], swizzled
  __shared__ __attribute__((aligned(16))) u16 Pl[4][16 * 128]; // per-wave, swizzled
  __shared__ __attribute__((aligned(16))) float maskf[Sn];

  const int tid  = threadIdx.x;
  const int wave = tid >> 6;
  const int lane = tid & 63;
  const int ln   = lane & 15;
  const int quad = lane >> 4;
  // XCD-grouping decode: bx = x + 8*(qt + 16*grp), bh = grp*8 + x
  const int bx  = blockIdx.x;
  const int x   = bx & 7;
  const int qt  = (bx >> 3) & 15;
  const int grp = bx >> 7;
  const int bh  = grp * 8 + x;
  const int b   = bh >> 4;
  const int h   = bh & 15;

  const int mt = flags[1];
  for (int i = tid; i < Sn; i += 256) {
    const int idx = b * Sn + i;
    int nz;
    if (mt == 0)      nz = ((const int*)mask)[idx] != 0;
    else if (mt == 1) nz = ((const signed char*)mask)[idx] != 0;
    else if (mt == 2) nz = ((const u16*)mask)[idx] != 0;
    else              nz = ((const unsigned*)mask)[idx] != 0;
    maskf[i] = nz ? -1e9f : 0.0f;
  }

  // Q fragments (A-operand: m=lane&15, k=quad*8+j); Q pre-scaled by 1/8
  const size_t qoff = (size_t)(b * Sn + qt * 64 + wave * 16 + ln) * Hn + h * DHn;
  bf16x8 qf0 = *(const bf16x8*)&Qb[qoff + quad * 8];
  bf16x8 qf1 = *(const bf16x8*)&Qb[qoff + 32 + quad * 8];

  float mrun[4], lrun[4];
#pragma unroll
  for (int r = 0; r < 4; ++r) { mrun[r] = -INFINITY; lrun[r] = 0.0f; }
  f32x4 acc[4] = {};

  const int kr = tid >> 1, kh = tid & 1;   // K stage: 2 threads/row (64B each)
  const int vd = tid >> 2, vs = tid & 3;   // V stage: 4 threads/row (64B each)
  char* pw  = (char*)Pl[wave];
  char* KsB = (char*)Ks;
  char* VtB = (char*)Vt;

  const int kwb = kr * 128 + kh * 64;      // K write byte base (unswizzled)
  const int ksw = (kr & 7) << 4;
  const int vwb = vd * 256 + vs * 64;      // V write byte base
  const int vsw = (vd & 7) << 4;
  const int rsw = (ln & 7) << 4;           // read-side swizzle (row&7 == ln&7)

  for (int t8 = 0; t8 < 8; ++t8) {
    const int kv0 = t8 * 128;
    __syncthreads();  // previous Ks/Vt fully consumed
    {
      const u16* g = &Kb[(size_t)(b * Sn + kv0 + kr) * Hn + h * DHn + kh * 32];
#pragma unroll
      for (int j = 0; j < 4; ++j)
        *(bf16x8*)(KsB + ((kwb + j * 16) ^ ksw)) = *(const bf16x8*)(g + j * 8);
    }
    {
      const u16* g = &Vbt[(size_t)(b * Sn + h * DHn + vd) * Sn + kv0 + vs * 32];
#pragma unroll
      for (int j = 0; j < 4; ++j)
        *(bf16x8*)(VtB + ((vwb + j * 16) ^ vsw)) = *(const bf16x8*)(g + j * 8);
    }
    __syncthreads();

    // S = Q K^T from LDS (B-operand: n=lane&15 -> kv row, k=quad*8+j -> d)
    f32x4 sc[8];
#pragma unroll
    for (int t = 0; t < 8; ++t) {
      const int rb = (t * 16 + ln) * 128;
      bf16x8 kf0 = *(const bf16x8*)(KsB + ((rb + quad * 16) ^ rsw));
      bf16x8 kf1 = *(const bf16x8*)(KsB + ((rb + 64 + quad * 16) ^ rsw));
      f32x4 z = {};
      z = __builtin_amdgcn_mfma_f32_16x16x32_bf16(qf0, kf0, z, 0, 0, 0);
      z = __builtin_amdgcn_mfma_f32_16x16x32_bf16(qf1, kf1, z, 0, 0, 0);
      sc[t] = z;
    }
    float mf[8];
#pragma unroll
    for (int t = 0; t < 8; ++t) mf[t] = maskf[kv0 + t * 16 + ln];
#pragma unroll
    for (int t = 0; t < 8; ++t)
#pragma unroll
      for (int r = 0; r < 4; ++r) sc[t][r] += mf[t];

    // online softmax per Q-row; 16-lane reductions on the VALU via DPP.
    float al[4], mx[4];
#pragma unroll
    for (int r = 0; r < 4; ++r) {
      float v = sc[0][r];
#pragma unroll
      for (int t = 1; t < 8; ++t) v = fmaxf(v, sc[t][r]);
      v = row16_max(v);
      const float mnew = fmaxf(mrun[r], v);
      al[r] = __expf(mrun[r] - mnew);
      mrun[r] = mnew;
      mx[r] = mnew;
    }
#pragma unroll
    for (int r = 0; r < 4; ++r) {
      float s = 0.0f;
#pragma unroll
      for (int t = 0; t < 8; ++t) {
        const float p = __expf(sc[t][r] - mx[r]);
        sc[t][r] = p;
        s += p;
      }
      s = row16_sum(s);
      lrun[r] = lrun[r] * al[r] + s;
    }
    // P: C-layout -> per-wave LDS strip -> A-layout (same-wave, no barrier)
#pragma unroll
    for (int t = 0; t < 8; ++t)
#pragma unroll
      for (int r = 0; r < 4; ++r) {
        const int prow = quad * 4 + r;
        *(u16*)(pw + ((prow * 256 + (t * 16 + ln) * 2) ^ ((prow & 7) << 4))) =
            f2bf(sc[t][r]);
      }
#pragma unroll
    for (int dt = 0; dt < 4; ++dt)
#pragma unroll
      for (int r = 0; r < 4; ++r) acc[dt][r] *= al[r];
    bf16x8 pa[4];
#pragma unroll
    for (int c = 0; c < 4; ++c)
      pa[c] = *(const bf16x8*)(pw + ((ln * 256 + c * 64 + quad * 16) ^ rsw));
#pragma unroll
    for (int dt = 0; dt < 4; ++dt) {
      const int vrb = (dt * 16 + ln) * 256;
#pragma unroll
      for (int c = 0; c < 4; ++c) {
        bf16x8 vb = *(const bf16x8*)(VtB + ((vrb + c * 64 + quad * 16) ^ rsw));
        acc[dt] = __builtin_amdgcn_mfma_f32_16x16x32_bf16(pa[c], vb, acc[dt], 0, 0, 0);
      }
    }
  }

#pragma unroll
  for (int dt = 0; dt < 4; ++dt)
#pragma unroll
    for (int r = 0; r < 4; ++r) {
      const int s = qt * 64 + wave * 16 + quad * 4 + r;
      Ctx[(size_t)(b * Sn + s) * Hn + h * DHn + dt * 16 + ln] = f2bf(acc[dt][r] / lrun[r]);
    }
}

extern "C" void kernel_launch(void* const* d_in, const int* in_sizes, int n_in,
                              void* d_out, int out_size, void* d_ws, size_t ws_size,
                              hipStream_t stream) {
  const float* v    = (const float*)d_in[0];
  const float* k    = (const float*)d_in[1];
  const float* q    = (const float*)d_in[2];
  const void*  mask = d_in[3];
  const float* Wq   = (const float*)d_in[4];
  const float* bq   = (const float*)d_in[5];
  const float* Wk   = (const float*)d_in[6];
  const float* bk   = (const float*)d_in[7];
  const float* Wv   = (const float*)d_in[8];
  const float* bv   = (const float*)d_in[9];
  const float* Wm   = (const float*)d_in[10];
  const float* bm   = (const float*)d_in[11];

  // ws layout (56MB + 8B, extents proven safe in round 2/3):
  char* ws = (char*)d_ws;
  u16* qc  = (u16*)(ws);                  // 16MB, consumed by Q-proj -> reused as Vbt
  u16* kc  = (u16*)(ws + (16u << 20));    // 16MB, consumed by K-proj -> reused as Cx
  u16* vc  = (u16*)(ws + (32u << 20));    // 16MB
  u16* Wqc = (u16*)(ws + (48u << 20));    // 2MB each
  u16* Wkc = Wqc + (1u << 20);
  u16* Wvc = Wkc + (1u << 20);
  u16* Wmc = Wvc + (1u << 20);
  int* flags = (int*)(ws + (56u << 20));
  u16* Vbt = qc;
  u16* Cx  = kc;
  u16* Qb  = (u16*)d_out;                 // d_out (32MB f32) hosts Qb+Kb bf16
  u16* Kb  = Qb + (size_t)Mn * Hn;

  sniff_k<<<1, 256, 0, stream>>>(mask, flags);
  convert3<<<3 * 4096, 256, 0, stream>>>(q, k, v, qc, kc, vc);
  convertW<<<4 * 512, 256, 0, stream>>>(Wq, Wk, Wv, Wm, Wqc, Wkc, Wvc, Wmc);

  dim3 blk(256);
  // Fused Q+K projections: 1024 blocks = 4/CU. (V can't fuse: writes over qc
  // which Q-proj reads.)
  gemm_qk<<<dim3(Mn / 128, Hn / 128, 2), blk, 0, stream>>>(
      qc, Wqc, bq, Qb, kc, Wkc, bk, Kb);
  dim3 grid(Mn / 128, Hn / 128);
  gemm_bt<2><<<grid, blk, 0, stream>>>(vc, Wvc, bv, Vbt, 1.0f);   // over qc
  attn<<<dim3(Bn * NHn * (Sn / 64)), blk, 0, stream>>>(Qb, Kb, Vbt, mask, flags, Cx); // over kc
  gemm_bt<1><<<grid, blk, 0, stream>>>(Cx, Wmc, bm, d_out, 1.0f);
}

// Round 7
// 345.716 us; speedup vs baseline: 1.4449x; 1.0255x over previous
//
#include <hip/hip_runtime.h>
#include <hip/hip_bf16.h>

// B=8, S=1024, H=1024, NH=16, DH=64. Inputs fp32 (proven r1/r4), output f32
// (proven r4), mask dtype sniffed 4-way. All GEMMs pure bf16 after a convert
// pass; V projection writes per-head-TRANSPOSED Vbt so attention stages V
// coalesced with no scatter.
// r2: attn blockIdx XCD-grouping — K/V L2-hot (FETCH 139MB->25MB, confirmed).
// r3: unpadded XOR-swizzled LDS, 53248B -> 3 blocks/CU; P-barrier dropped.
// r5: softmax reductions off the LDS pipe (attn 129.5 -> 105.7us, confirmed).
// r6: Q+K proj fused; BK=64; staged-source read swizzle (reads bank-balanced).
// r7a GEMM: double-buffered LDS (64KB, 2 blocks/CU), stage(t+1) issued before
//   compute(t), ONE barrier/step — hides the ~500cy staging latency the
//   2-barrier m97 structure exposes every K-step.
// r7b attn: swapped QK^T (mfma(K,Q)) — fragments identical, C becomes [kv][q];
//   softmax is in-lane (tree + 2 shfl_xor), P written as 8 packed ds_write_b64
//   (was 32 scalar), al/lrun redistributed via 4 shfl. PV/C-write unchanged.
#define Bn 8
#define Sn 1024
#define Hn 1024
#define NHn 16
#define DHn 64
#define Mn (Bn * Sn)

typedef unsigned short u16;
typedef short bf16x8 __attribute__((ext_vector_type(8)));
typedef unsigned short u16x4 __attribute__((ext_vector_type(4)));
typedef float f32x4 __attribute__((ext_vector_type(4)));

__device__ __forceinline__ u16 f2bf(float x) {
  union { __hip_bfloat16 h; u16 u; } cv;
  cv.h = __float2bfloat16(x);
  return cv.u;
}

__device__ __forceinline__ void async_ld16(void* lds, const void* g) {
  __builtin_amdgcn_global_load_lds(
      (const __attribute__((address_space(1))) void*)g,
      (__attribute__((address_space(3))) void*)lds, 16, 0, 0);
}

// ---------------------------------------------------------------------------
// Mask dtype sniffer: flags[1] = 0:i32 1:i8 2:bf16 3:f32 (f32 before bf16).
// ---------------------------------------------------------------------------
__global__ __launch_bounds__(256) void sniff_k(const void* __restrict__ mask,
                                               int* __restrict__ flags) {
  __shared__ int viol;
  if (threadIdx.x == 0) viol = 0;
  __syncthreads();
  const unsigned* mw = (const unsigned*)mask;
  int vb = 0;
#pragma unroll
  for (int j = 0; j < 8; ++j) {
    unsigned v = mw[threadIdx.x * 8 + j];          // first 8192B valid for all dtypes
    if (v > 1u) vb |= 1;
    if ((v & 0xFEFEFEFEu) != 0u) vb |= 2;
    if (!(v == 0u || v == 0x3F800000u)) vb |= 4;
    unsigned h0 = v & 0xFFFFu, h1 = v >> 16;
    if (!((h0 == 0u || h0 == 0x3F80u) && (h1 == 0u || h1 == 0x3F80u))) vb |= 8;
  }
  if (vb) atomicOr(&viol, vb);
  __syncthreads();
  if (threadIdx.x == 0) {
    int mt;
    if (!(viol & 1))      mt = 0;
    else if (!(viol & 2)) mt = 1;
    else if (!(viol & 4)) mt = 3;
    else if (!(viol & 8)) mt = 2;
    else                  mt = 0;
    flags[1] = mt;
  }
}

// fp32 -> bf16: three equal tensors of 8388608 elems, one thread = 8 elems.
__global__ __launch_bounds__(256) void convert3(
    const float* __restrict__ a, const float* __restrict__ b,
    const float* __restrict__ c, u16* __restrict__ da,
    u16* __restrict__ db, u16* __restrict__ dc) {
  const int seg = blockIdx.x >> 12;                 // 4096 blocks per tensor
  const int bid = blockIdx.x & 4095;
  const float* s = seg == 0 ? a : seg == 1 ? b : c;
  u16* d        = seg == 0 ? da : seg == 1 ? db : dc;
  const int i = (bid * 256 + threadIdx.x) * 8;
  f32x4 lo = *(const f32x4*)(s + i);
  f32x4 hi = *(const f32x4*)(s + i + 4);
  bf16x8 o;
#pragma unroll
  for (int j = 0; j < 4; ++j) { o[j] = (short)f2bf(lo[j]); o[4 + j] = (short)f2bf(hi[j]); }
  *(bf16x8*)(d + i) = o;
}

// fp32 -> bf16: four 1048576-elem weights.
__global__ __launch_bounds__(256) void convertW(
    const float* __restrict__ a, const float* __restrict__ b,
    const float* __restrict__ c, const float* __restrict__ e,
    u16* __restrict__ da, u16* __restrict__ db,
    u16* __restrict__ dc, u16* __restrict__ de) {
  const int seg = blockIdx.x >> 9;                  // 512 blocks per tensor
  const int bid = blockIdx.x & 511;
  const float* s = seg == 0 ? a : seg == 1 ? b : seg == 2 ? c : e;
  u16* d        = seg == 0 ? da : seg == 1 ? db : seg == 2 ? dc : de;
  const int i = (bid * 256 + threadIdx.x) * 8;
  f32x4 lo = *(const f32x4*)(s + i);
  f32x4 hi = *(const f32x4*)(s + i + 4);
  bf16x8 o;
#pragma unroll
  for (int j = 0; j < 4; ++j) { o[j] = (short)f2bf(lo[j]); o[4 + j] = (short)f2bf(hi[j]); }
  *(bf16x8*)(d + i) = o;
}

// ---------------------------------------------------------------------------
// O = (X[8192,1024] @ W[1024,1024]^T + bias)*scale, bf16 in, fp32 accum.
// 128x128 tile, BK=64, DOUBLE-BUFFERED (r7a): stage(t+1) issued before
// compute(t); one barrier per step (compiler's vmcnt(0)-before-barrier then
// drains loads that had the whole compute phase to complete).
// Staging: lane loads pre-swizzled global chunk ((l&7)^(row&7)); frag reads
// XOR back -> bank-balanced (8 lanes per 4-bank group = optimal for b128).
// OMODE 0: bf16 row-major. 1: f32 row-major. 2: bf16 per-head transposed
// Vbt[(b*1024+col)*1024 + s] with packed b64 stores (V projection).
// ---------------------------------------------------------------------------
template <int OMODE>
__device__ __forceinline__ void gemm_core(
    u16* As, u16* Bs, const u16* __restrict__ X, const u16* __restrict__ W,
    const float* __restrict__ bias, void* __restrict__ O, float scale)
{
  const int tid  = threadIdx.x;
  const int wave = tid >> 6;
  const int lane = tid & 63;
  const int ln   = lane & 15;
  const int quad = lane >> 4;
  const int m0 = blockIdx.x * 128;
  const int n0 = blockIdx.y * 128;
  const int wm = (wave & 1) * 64;
  const int wn = (wave >> 1) * 64;
  const int r8 = tid >> 3;                       // staging row within 32-group ×4
  const int cg = ((tid & 7) ^ (r8 & 7)) * 8;     // pre-swizzled global col chunk
  const int rsw = ln & 7;                        // read-side row swizzle bits

  f32x4 acc[4][4] = {};

  auto STAGE = [&](int buf, int k0) {
    char* Ad = (char*)As + buf * 16384 + wave * 1024;   // gll dest: uniform+lane*16
    char* Bd = (char*)Bs + buf * 16384 + wave * 1024;
#pragma unroll
    for (int j = 0; j < 4; ++j) {
      async_ld16(Ad + j * 4096, X + (size_t)(m0 + j * 32 + r8) * 1024 + k0 + cg);
      async_ld16(Bd + j * 4096, W + (size_t)(n0 + j * 32 + r8) * 1024 + k0 + cg);
    }
  };

  STAGE(0, 0);
  __syncthreads();                       // buf0 ready
  for (int step = 0; step < 16; ++step) {
    const int cur = step & 1;
    if (step < 15) STAGE(cur ^ 1, (step + 1) * 64);   // in flight under compute
    const char* Ab = (const char*)As + cur * 16384;
    const char* Bb = (const char*)Bs + cur * 16384;
#pragma unroll
    for (int s = 0; s < 2; ++s) {
      const int co = ((s * 4 + quad) ^ rsw) * 16;     // swizzled 16B chunk
      bf16x8 af[4], bfr[4];
#pragma unroll
      for (int t = 0; t < 4; ++t)
        af[t] = *(const bf16x8*)(Ab + (wm + t * 16 + ln) * 128 + co);
#pragma unroll
      for (int t = 0; t < 4; ++t)
        bfr[t] = *(const bf16x8*)(Bb + (wn + t * 16 + ln) * 128 + co);
#pragma unroll
      for (int i = 0; i < 4; ++i)
#pragma unroll
        for (int j = 0; j < 4; ++j)
          acc[i][j] = __builtin_amdgcn_mfma_f32_16x16x32_bf16(af[i], bfr[j], acc[i][j], 0, 0, 0);
    }
    __syncthreads();   // reads of buf[cur] done; stage(step+1) drained
  }

  // C/D: col = lane&15 (+16j), row = quad*4 + r
  if (OMODE == 2) {
    const int bb = m0 >> 10;          // batch (tile never crosses batches)
    const int sb = m0 & 1023;
#pragma unroll
    for (int j = 0; j < 4; ++j) {
      const int col = n0 + wn + j * 16 + ln;
      const float bv = bias[col];
#pragma unroll
      for (int i = 0; i < 4; ++i) {
        const int sl = sb + wm + i * 16 + quad * 4;
        u16x4 pk;
#pragma unroll
        for (int r = 0; r < 4; ++r) pk[r] = f2bf((acc[i][j][r] + bv) * scale);
        *(u16x4*)&((u16*)O)[((size_t)(bb * 1024 + col)) * 1024 + sl] = pk;
      }
    }
  } else {
#pragma unroll
    for (int j = 0; j < 4; ++j) {
      const int col = n0 + wn + j * 16 + ln;
      const float bv = bias[col];
#pragma unroll
      for (int i = 0; i < 4; ++i) {
        const int rowb = m0 + wm + i * 16 + quad * 4;
#pragma unroll
        for (int r = 0; r < 4; ++r) {
          const float val = (acc[i][j][r] + bv) * scale;
          const size_t idx = (size_t)(rowb + r) * 1024 + col;
          if (OMODE == 1) ((float*)O)[idx] = val;
          else            ((u16*)O)[idx]   = f2bf(val);
        }
      }
    }
  }
}

template <int OMODE>
__global__ __launch_bounds__(256, 2) void gemm_bt(
    const u16* __restrict__ X, const u16* __restrict__ W,
    const float* __restrict__ bias, void* __restrict__ O, float scale)
{
  __shared__ __attribute__((aligned(16))) u16 As[2 * 128 * 64];
  __shared__ __attribute__((aligned(16))) u16 Bs[2 * 128 * 64];
  gemm_core<OMODE>(As, Bs, X, W, bias, O, scale);
}

// Fused Q-proj (z=0) + K-proj (z=1): independent inputs/outputs.
__global__ __launch_bounds__(256, 2) void gemm_qk(
    const u16* __restrict__ Xq, const u16* __restrict__ Wq,
    const float* __restrict__ bq, u16* __restrict__ Oq,
    const u16* __restrict__ Xk, const u16* __restrict__ Wk,
    const float* __restrict__ bk, u16* __restrict__ Ok)
{
  __shared__ __attribute__((aligned(16))) u16 As[2 * 128 * 64];
  __shared__ __attribute__((aligned(16))) u16 Bs[2 * 128 * 64];
  const int z = blockIdx.z;
  gemm_core<0>(As, Bs, z ? Xk : Xq, z ? Wk : Wq, z ? bk : bq,
               z ? (void*)Ok : (void*)Oq, z ? 1.0f : 0.125f);
}

// ---------------------------------------------------------------------------
// Flash attention v2: block = (b,h,64-row Q tile), 4 waves x 16 Q-rows,
// KV-tile 128 (8 iterations). K/V staged via LDS, V from pre-transposed Vbt.
// r2 XCD swizzle; r3 unpadded XOR-swizzled LDS (53248B, 3 blocks/CU), no
// P-barrier. r7b: SWAPPED QK^T — z = mfma(kf, qf) gives C[kv=quad*4+r][q=ln];
// each lane owns one Q-row's 32 scores -> in-lane softmax (tree + 2 shfl_xor),
// P packed as 8 ds_write_b64/iter. al/lrun redistributed to acc rows (q =
// quad*4+r) via shfl. pa read / PV / C-write identical to r6.
// ---------------------------------------------------------------------------
__global__ __launch_bounds__(256, 3) void attn(
    const u16* __restrict__ Qb, const u16* __restrict__ Kb,
    const u16* __restrict__ Vbt, const void* __restrict__ mask,
    const int* __restrict__ flags, u16* __restrict__ Ctx)
{
  __shared__ __attribute__((aligned(16))) u16 Ks[128 * 64];    // [kv][d], swizzled
  __shared__ __attribute__((aligned(16))) u16 Vt[64 * 128];    // [d][kv], swizzled
  __shared__ __attribute__((aligned(16))) u16 Pl[4][16 * 128]; // per-wave [q][kv]
  __shared__ __attribute__((aligned(16))) float maskf[Sn];

  const int tid  = threadIdx.x;
  const int wave = tid >> 6;
  const int lane = tid & 63;
  const int ln   = lane & 15;
  const int quad = lane >> 4;
  // XCD-grouping decode: bx = x + 8*(qt + 16*grp), bh = grp*8 + x
  const int bx  = blockIdx.x;
  const int x   = bx & 7;
  const int qt  = (bx >> 3) & 15;
  const int grp = bx >> 7;
  const int bh  = grp * 8 + x;
  const int b   = bh >> 4;
  const int h   = bh & 15;

  const int mt = flags[1];
  for (int i = tid; i < Sn; i += 256) {
    const int idx = b * Sn + i;
    int nz;
    if (mt == 0)      nz = ((const int*)mask)[idx] != 0;
    else if (mt == 1) nz = ((const signed char*)mask)[idx] != 0;
    else if (mt == 2) nz = ((const u16*)mask)[idx] != 0;
    else              nz = ((const unsigned*)mask)[idx] != 0;
    maskf[i] = nz ? -1e9f : 0.0f;
  }

  // Q fragments (B-operand in swapped QK^T: n=lane&15 -> Q-row, k=quad*8+j -> d);
  // identical bytes to the old A-operand load. Q pre-scaled by 1/8.
  const size_t qoff = (size_t)(b * Sn + qt * 64 + wave * 16 + ln) * Hn + h * DHn;
  bf16x8 qf0 = *(const bf16x8*)&Qb[qoff + quad * 8];
  bf16x8 qf1 = *(const bf16x8*)&Qb[qoff + 32 + quad * 8];

  float mrun = -INFINITY, lrun = 0.0f;   // this lane's Q-row (ln) running stats
  f32x4 acc[4] = {};

  const int kr = tid >> 1, kh = tid & 1;   // K stage: 2 threads/row (64B each)
  const int vd = tid >> 2, vs = tid & 3;   // V stage: 4 threads/row (64B each)
  char* pw  = (char*)Pl[wave];
  char* KsB = (char*)Ks;
  char* VtB = (char*)Vt;

  const int kwb = kr * 128 + kh * 64;      // K write byte base (unswizzled)
  const int ksw = (kr & 7) << 4;
  const int vwb = vd * 256 + vs * 64;      // V write byte base
  const int vsw = (vd & 7) << 4;
  const int rsw = (ln & 7) << 4;           // read-side swizzle (row&7 == ln&7)
  const int pwb = ln * 256;                // P row base (row = q = ln)
  const int psw = (ln & 7) << 4;

  for (int t8 = 0; t8 < 8; ++t8) {
    const int kv0 = t8 * 128;
    __syncthreads();  // previous Ks/Vt fully consumed
    {
      const u16* g = &Kb[(size_t)(b * Sn + kv0 + kr) * Hn + h * DHn + kh * 32];
#pragma unroll
      for (int j = 0; j < 4; ++j)
        *(bf16x8*)(KsB + ((kwb + j * 16) ^ ksw)) = *(const bf16x8*)(g + j * 8);
    }
    {
      const u16* g = &Vbt[(size_t)(b * Sn + h * DHn + vd) * Sn + kv0 + vs * 32];
#pragma unroll
      for (int j = 0; j < 4; ++j)
        *(bf16x8*)(VtB + ((vwb + j * 16) ^ vsw)) = *(const bf16x8*)(g + j * 8);
    }
    __syncthreads();

    // S = K Q^T from LDS: A=K (m=ln -> kv row t*16+ln, k=quad*8+j -> d),
    // B=Q. C[row=quad*4+r -> kv][col=ln -> q].
    f32x4 sc[8];
#pragma unroll
    for (int t = 0; t < 8; ++t) {
      const int rb = (t * 16 + ln) * 128;
      bf16x8 kf0 = *(const bf16x8*)(KsB + ((rb + quad * 16) ^ rsw));
      bf16x8 kf1 = *(const bf16x8*)(KsB + ((rb + 64 + quad * 16) ^ rsw));
      f32x4 z = {};
      z = __builtin_amdgcn_mfma_f32_16x16x32_bf16(kf0, qf0, z, 0, 0, 0);
      z = __builtin_amdgcn_mfma_f32_16x16x32_bf16(kf1, qf1, z, 0, 0, 0);
      sc[t] = z;   // sc[t][r] = S[kv = kv0 + 16t + quad*4 + r][q-row = ln]
    }
    // mask by kv (vectorized: r is 4 consecutive kv)
#pragma unroll
    for (int t = 0; t < 8; ++t) {
      const f32x4 mf4 = *(const f32x4*)&maskf[kv0 + t * 16 + quad * 4];
#pragma unroll
      for (int r = 0; r < 4; ++r) sc[t][r] += mf4[r];
    }

    // in-lane online softmax for Q-row ln: tree max over 32 regs + 2 shfl_xor
    f32x4 mm = sc[0];
#pragma unroll
    for (int t = 1; t < 8; ++t)
#pragma unroll
      for (int r = 0; r < 4; ++r) mm[r] = fmaxf(mm[r], sc[t][r]);
    float vmax = fmaxf(fmaxf(mm[0], mm[1]), fmaxf(mm[2], mm[3]));
    vmax = fmaxf(vmax, __shfl_xor(vmax, 16));
    vmax = fmaxf(vmax, __shfl_xor(vmax, 32));
    const float mnew = fmaxf(mrun, vmax);
    const float al = __expf(mrun - mnew);
    mrun = mnew;
    float ssum = 0.0f;
#pragma unroll
    for (int t = 0; t < 8; ++t)
#pragma unroll
      for (int r = 0; r < 4; ++r) {
        const float p = __expf(sc[t][r] - mnew);
        sc[t][r] = p;
        ssum += p;
      }
    ssum += __shfl_xor(ssum, 16);
    ssum += __shfl_xor(ssum, 32);
    lrun = lrun * al + ssum;

    // P -> LDS [q=ln][kv], packed 8B writes (r consecutive kv), swizzled.
#pragma unroll
    for (int t = 0; t < 8; ++t) {
      u16x4 pk;
#pragma unroll
      for (int r = 0; r < 4; ++r) pk[r] = f2bf(sc[t][r]);
      *(u16x4*)(pw + ((pwb + t * 32 + quad * 8) ^ psw)) = pk;
    }

    // rescale acc: acc rows are q = quad*4+r -> fetch those rows' al
    float alr[4];
#pragma unroll
    for (int r = 0; r < 4; ++r) alr[r] = __shfl(al, quad * 4 + r);
#pragma unroll
    for (int dt = 0; dt < 4; ++dt)
#pragma unroll
      for (int r = 0; r < 4; ++r) acc[dt][r] *= alr[r];

    // PV: A=P (m=ln -> q, k=quad*8+j -> kv), B=V. Same-wave P write->read.
    bf16x8 pa[4];
#pragma unroll
    for (int c = 0; c < 4; ++c)
      pa[c] = *(const bf16x8*)(pw + ((pwb + c * 64 + quad * 16) ^ psw));
#pragma unroll
    for (int dt = 0; dt < 4; ++dt) {
      const int vrb = (dt * 16 + ln) * 256;
#pragma unroll
      for (int c = 0; c < 4; ++c) {
        bf16x8 vb = *(const bf16x8*)(VtB + ((vrb + c * 64 + quad * 16) ^ rsw));
        acc[dt] = __builtin_amdgcn_mfma_f32_16x16x32_bf16(pa[c], vb, acc[dt], 0, 0, 0);
      }
    }
  }

  // acc[dt][r] = O[q = quad*4+r][d = dt*16+ln]; divide by that row's lrun
  float lr[4];
#pragma unroll
  for (int r = 0; r < 4; ++r) lr[r] = __shfl(lrun, quad * 4 + r);
#pragma unroll
  for (int dt = 0; dt < 4; ++dt)
#pragma unroll
    for (int r = 0; r < 4; ++r) {
      const int s = qt * 64 + wave * 16 + quad * 4 + r;
      Ctx[(size_t)(b * Sn + s) * Hn + h * DHn + dt * 16 + ln] = f2bf(acc[dt][r] / lr[r]);
    }
}

extern "C" void kernel_launch(void* const* d_in, const int* in_sizes, int n_in,
                              void* d_out, int out_size, void* d_ws, size_t ws_size,
                              hipStream_t stream) {
  const float* v    = (const float*)d_in[0];
  const float* k    = (const float*)d_in[1];
  const float* q    = (const float*)d_in[2];
  const void*  mask = d_in[3];
  const float* Wq   = (const float*)d_in[4];
  const float* bq   = (const float*)d_in[5];
  const float* Wk   = (const float*)d_in[6];
  const float* bk   = (const float*)d_in[7];
  const float* Wv   = (const float*)d_in[8];
  const float* bv   = (const float*)d_in[9];
  const float* Wm   = (const float*)d_in[10];
  const float* bm   = (const float*)d_in[11];

  // ws layout (56MB + 8B, extents proven safe in round 2/3):
  char* ws = (char*)d_ws;
  u16* qc  = (u16*)(ws);                  // 16MB, consumed by Q-proj -> reused as Vbt
  u16* kc  = (u16*)(ws + (16u << 20));    // 16MB, consumed by K-proj -> reused as Cx
  u16* vc  = (u16*)(ws + (32u << 20));    // 16MB
  u16* Wqc = (u16*)(ws + (48u << 20));    // 2MB each
  u16* Wkc = Wqc + (1u << 20);
  u16* Wvc = Wkc + (1u << 20);
  u16* Wmc = Wvc + (1u << 20);
  int* flags = (int*)(ws + (56u << 20));
  u16* Vbt = qc;
  u16* Cx  = kc;
  u16* Qb  = (u16*)d_out;                 // d_out (32MB f32) hosts Qb+Kb bf16
  u16* Kb  = Qb + (size_t)Mn * Hn;

  sniff_k<<<1, 256, 0, stream>>>(mask, flags);
  convert3<<<3 * 4096, 256, 0, stream>>>(q, k, v, qc, kc, vc);
  convertW<<<4 * 512, 256, 0, stream>>>(Wq, Wk, Wv, Wm, Wqc, Wkc, Wvc, Wmc);

  dim3 blk(256);
  // Fused Q+K projections (independent in/out).
  gemm_qk<<<dim3(Mn / 128, Hn / 128, 2), blk, 0, stream>>>(
      qc, Wqc, bq, Qb, kc, Wkc, bk, Kb);
  dim3 grid(Mn / 128, Hn / 128);
  gemm_bt<2><<<grid, blk, 0, stream>>>(vc, Wvc, bv, Vbt, 1.0f);   // over qc
  attn<<<dim3(Bn * NHn * (Sn / 64)), blk, 0, stream>>>(Qb, Kb, Vbt, mask, flags, Cx); // over kc
  gemm_bt<1><<<grid, blk, 0, stream>>>(Cx, Wmc, bm, d_out, 1.0f);
}

// Round 8
// 331.144 us; speedup vs baseline: 1.5085x; 1.0440x over previous
//
#include <hip/hip_runtime.h>
#include <hip/hip_bf16.h>

// B=8, S=1024, H=1024, NH=16, DH=64. Inputs fp32 (proven r1/r4), output f32
// (proven r4), mask dtype sniffed 4-way. All GEMMs pure bf16 after a convert
// pass; V projection writes per-head-TRANSPOSED Vbt so attention stages V
// coalesced with no scatter.
// r2: attn blockIdx XCD-grouping — K/V L2-hot (FETCH 139MB->25MB, confirmed).
// r3: unpadded XOR-swizzled LDS, 53248B -> 3 blocks/CU; P-barrier dropped.
// r5: softmax reductions off the LDS pipe (attn 129.5 -> 105.7us, confirmed).
// r6: Q+K proj fused; BK=64; staged-source read swizzle.
// r7a: GEMM double-buffer (one barrier/step). r7b: swapped QK^T, in-lane
//   softmax (VALU 40->33, VGPR 84->68, confirmed cheaper; dur-neutral).
// r8a GEMM: XCD-chunked grid remap — each XCD owns 8 x-tiles x all y-tiles;
//   per-XCD L2 set = 2MB X-panels + 2MB W = 4MB -> staging is L2-hit
//   (~200cy), so the r7a dbuf drain (compute ~300cy) finally hides it.
// r8b attn: K/V reg-prefetch one tile ahead (r1 structure, now safe: its r1
//   regression was the L2 thrash r2 eliminated) — stage latency off the
//   serial chain.
#define Bn 8
#define Sn 1024
#define Hn 1024
#define NHn 16
#define DHn 64
#define Mn (Bn * Sn)

typedef unsigned short u16;
typedef short bf16x8 __attribute__((ext_vector_type(8)));
typedef unsigned short u16x4 __attribute__((ext_vector_type(4)));
typedef float f32x4 __attribute__((ext_vector_type(4)));

__device__ __forceinline__ u16 f2bf(float x) {
  union { __hip_bfloat16 h; u16 u; } cv;
  cv.h = __float2bfloat16(x);
  return cv.u;
}

__device__ __forceinline__ void async_ld16(void* lds, const void* g) {
  __builtin_amdgcn_global_load_lds(
      (const __attribute__((address_space(1))) void*)g,
      (__attribute__((address_space(3))) void*)lds, 16, 0, 0);
}

// ---------------------------------------------------------------------------
// Mask dtype sniffer: flags[1] = 0:i32 1:i8 2:bf16 3:f32 (f32 before bf16).
// ---------------------------------------------------------------------------
__global__ __launch_bounds__(256) void sniff_k(const void* __restrict__ mask,
                                               int* __restrict__ flags) {
  __shared__ int viol;
  if (threadIdx.x == 0) viol = 0;
  __syncthreads();
  const unsigned* mw = (const unsigned*)mask;
  int vb = 0;
#pragma unroll
  for (int j = 0; j < 8; ++j) {
    unsigned v = mw[threadIdx.x * 8 + j];          // first 8192B valid for all dtypes
    if (v > 1u) vb |= 1;
    if ((v & 0xFEFEFEFEu) != 0u) vb |= 2;
    if (!(v == 0u || v == 0x3F800000u)) vb |= 4;
    unsigned h0 = v & 0xFFFFu, h1 = v >> 16;
    if (!((h0 == 0u || h0 == 0x3F80u) && (h1 == 0u || h1 == 0x3F80u))) vb |= 8;
  }
  if (vb) atomicOr(&viol, vb);
  __syncthreads();
  if (threadIdx.x == 0) {
    int mt;
    if (!(viol & 1))      mt = 0;
    else if (!(viol & 2)) mt = 1;
    else if (!(viol & 4)) mt = 3;
    else if (!(viol & 8)) mt = 2;
    else                  mt = 0;
    flags[1] = mt;
  }
}

// fp32 -> bf16: three equal tensors of 8388608 elems, one thread = 8 elems.
__global__ __launch_bounds__(256) void convert3(
    const float* __restrict__ a, const float* __restrict__ b,
    const float* __restrict__ c, u16* __restrict__ da,
    u16* __restrict__ db, u16* __restrict__ dc) {
  const int seg = blockIdx.x >> 12;                 // 4096 blocks per tensor
  const int bid = blockIdx.x & 4095;
  const float* s = seg == 0 ? a : seg == 1 ? b : c;
  u16* d        = seg == 0 ? da : seg == 1 ? db : dc;
  const int i = (bid * 256 + threadIdx.x) * 8;
  f32x4 lo = *(const f32x4*)(s + i);
  f32x4 hi = *(const f32x4*)(s + i + 4);
  bf16x8 o;
#pragma unroll
  for (int j = 0; j < 4; ++j) { o[j] = (short)f2bf(lo[j]); o[4 + j] = (short)f2bf(hi[j]); }
  *(bf16x8*)(d + i) = o;
}

// fp32 -> bf16: four 1048576-elem weights.
__global__ __launch_bounds__(256) void convertW(
    const float* __restrict__ a, const float* __restrict__ b,
    const float* __restrict__ c, const float* __restrict__ e,
    u16* __restrict__ da, u16* __restrict__ db,
    u16* __restrict__ dc, u16* __restrict__ de) {
  const int seg = blockIdx.x >> 9;                  // 512 blocks per tensor
  const int bid = blockIdx.x & 511;
  const float* s = seg == 0 ? a : seg == 1 ? b : seg == 2 ? c : e;
  u16* d        = seg == 0 ? da : seg == 1 ? db : seg == 2 ? dc : de;
  const int i = (bid * 256 + threadIdx.x) * 8;
  f32x4 lo = *(const f32x4*)(s + i);
  f32x4 hi = *(const f32x4*)(s + i + 4);
  bf16x8 o;
#pragma unroll
  for (int j = 0; j < 4; ++j) { o[j] = (short)f2bf(lo[j]); o[4 + j] = (short)f2bf(hi[j]); }
  *(bf16x8*)(d + i) = o;
}

// ---------------------------------------------------------------------------
// O = (X[8192,1024] @ W[1024,1024]^T + bias)*scale, bf16 in, fp32 accum.
// 128x128 tile, BK=64, double-buffered, ONE barrier/step.
// r8a XCD remap: dispatch id d=(x+64y)&7 -> XCD (r2-measured). new_x =
// (x&7)*8 + (x>>3), new_y = y: XCD i gets x-tiles [8i,8i+8) x all y; its 64
// blocks are all co-resident (2/CU x 32CU) -> X panels (2MB) + W (2MB) live
// in its 4MB L2 -> staging L2-hit, dbuf drain hidden under compute.
// Staging: lane loads pre-swizzled global chunk ((l&7)^(row&7)); frag reads
// XOR back -> bank-balanced. OMODE 0: bf16 row-major. 1: f32 row-major.
// 2: bf16 per-head transposed Vbt[(b*1024+col)*1024+s], packed b64 stores.
// ---------------------------------------------------------------------------
template <int OMODE>
__device__ __forceinline__ void gemm_core(
    u16* As, u16* Bs, const u16* __restrict__ X, const u16* __restrict__ W,
    const float* __restrict__ bias, void* __restrict__ O, float scale)
{
  const int tid  = threadIdx.x;
  const int wave = tid >> 6;
  const int lane = tid & 63;
  const int ln   = lane & 15;
  const int quad = lane >> 4;
  const int bxr  = blockIdx.x;                   // 0..63 (M tiles)
  const int m0 = ((bxr & 7) * 8 + (bxr >> 3)) * 128;   // XCD-chunked remap
  const int n0 = blockIdx.y * 128;
  const int wm = (wave & 1) * 64;
  const int wn = (wave >> 1) * 64;
  const int r8 = tid >> 3;                       // staging row within 32-group ×4
  const int cg = ((tid & 7) ^ (r8 & 7)) * 8;     // pre-swizzled global col chunk
  const int rsw = ln & 7;                        // read-side row swizzle bits

  f32x4 acc[4][4] = {};

  auto STAGE = [&](int buf, int k0) {
    char* Ad = (char*)As + buf * 16384 + wave * 1024;   // gll dest: uniform+lane*16
    char* Bd = (char*)Bs + buf * 16384 + wave * 1024;
#pragma unroll
    for (int j = 0; j < 4; ++j) {
      async_ld16(Ad + j * 4096, X + (size_t)(m0 + j * 32 + r8) * 1024 + k0 + cg);
      async_ld16(Bd + j * 4096, W + (size_t)(n0 + j * 32 + r8) * 1024 + k0 + cg);
    }
  };

  STAGE(0, 0);
  __syncthreads();                       // buf0 ready
  for (int step = 0; step < 16; ++step) {
    const int cur = step & 1;
    if (step < 15) STAGE(cur ^ 1, (step + 1) * 64);   // in flight under compute
    const char* Ab = (const char*)As + cur * 16384;
    const char* Bb = (const char*)Bs + cur * 16384;
#pragma unroll
    for (int s = 0; s < 2; ++s) {
      const int co = ((s * 4 + quad) ^ rsw) * 16;     // swizzled 16B chunk
      bf16x8 af[4], bfr[4];
#pragma unroll
      for (int t = 0; t < 4; ++t)
        af[t] = *(const bf16x8*)(Ab + (wm + t * 16 + ln) * 128 + co);
#pragma unroll
      for (int t = 0; t < 4; ++t)
        bfr[t] = *(const bf16x8*)(Bb + (wn + t * 16 + ln) * 128 + co);
#pragma unroll
      for (int i = 0; i < 4; ++i)
#pragma unroll
        for (int j = 0; j < 4; ++j)
          acc[i][j] = __builtin_amdgcn_mfma_f32_16x16x32_bf16(af[i], bfr[j], acc[i][j], 0, 0, 0);
    }
    __syncthreads();   // reads of buf[cur] done; stage(step+1) drained
  }

  // C/D: col = lane&15 (+16j), row = quad*4 + r
  if (OMODE == 2) {
    const int bb = m0 >> 10;          // batch (tile never crosses batches)
    const int sb = m0 & 1023;
#pragma unroll
    for (int j = 0; j < 4; ++j) {
      const int col = n0 + wn + j * 16 + ln;
      const float bv = bias[col];
#pragma unroll
      for (int i = 0; i < 4; ++i) {
        const int sl = sb + wm + i * 16 + quad * 4;
        u16x4 pk;
#pragma unroll
        for (int r = 0; r < 4; ++r) pk[r] = f2bf((acc[i][j][r] + bv) * scale);
        *(u16x4*)&((u16*)O)[((size_t)(bb * 1024 + col)) * 1024 + sl] = pk;
      }
    }
  } else {
#pragma unroll
    for (int j = 0; j < 4; ++j) {
      const int col = n0 + wn + j * 16 + ln;
      const float bv = bias[col];
#pragma unroll
      for (int i = 0; i < 4; ++i) {
        const int rowb = m0 + wm + i * 16 + quad * 4;
#pragma unroll
        for (int r = 0; r < 4; ++r) {
          const float val = (acc[i][j][r] + bv) * scale;
          const size_t idx = (size_t)(rowb + r) * 1024 + col;
          if (OMODE == 1) ((float*)O)[idx] = val;
          else            ((u16*)O)[idx]   = f2bf(val);
        }
      }
    }
  }
}

template <int OMODE>
__global__ __launch_bounds__(256, 2) void gemm_bt(
    const u16* __restrict__ X, const u16* __restrict__ W,
    const float* __restrict__ bias, void* __restrict__ O, float scale)
{
  __shared__ __attribute__((aligned(16))) u16 As[2 * 128 * 64];
  __shared__ __attribute__((aligned(16))) u16 Bs[2 * 128 * 64];
  gemm_core<OMODE>(As, Bs, X, W, bias, O, scale);
}

// Fused Q-proj (z=0) + K-proj (z=1): independent inputs/outputs. z offset in
// dispatch id is 512 = 0 mod 8, so the per-z XCD remap is unchanged.
__global__ __launch_bounds__(256, 2) void gemm_qk(
    const u16* __restrict__ Xq, const u16* __restrict__ Wq,
    const float* __restrict__ bq, u16* __restrict__ Oq,
    const u16* __restrict__ Xk, const u16* __restrict__ Wk,
    const float* __restrict__ bk, u16* __restrict__ Ok)
{
  __shared__ __attribute__((aligned(16))) u16 As[2 * 128 * 64];
  __shared__ __attribute__((aligned(16))) u16 Bs[2 * 128 * 64];
  const int z = blockIdx.z;
  gemm_core<0>(As, Bs, z ? Xk : Xq, z ? Wk : Wq, z ? bk : bq,
               z ? (void*)Ok : (void*)Oq, z ? 1.0f : 0.125f);
}

// ---------------------------------------------------------------------------
// Flash attention v2: block = (b,h,64-row Q tile), 4 waves x 16 Q-rows,
// KV-tile 128 (8 iterations). r2 XCD swizzle; r3 swizzled LDS (53248B,
// 3 blocks/CU); r7b swapped QK^T + in-lane softmax; r8b: K/V global->reg
// prefetch one tile ahead — loads issued right after the stage barrier,
// ds_written next iteration, so ~L2 latency hides under QK+softmax+PV.
// ---------------------------------------------------------------------------
__global__ __launch_bounds__(256, 3) void attn(
    const u16* __restrict__ Qb, const u16* __restrict__ Kb,
    const u16* __restrict__ Vbt, const void* __restrict__ mask,
    const int* __restrict__ flags, u16* __restrict__ Ctx)
{
  __shared__ __attribute__((aligned(16))) u16 Ks[128 * 64];    // [kv][d], swizzled
  __shared__ __attribute__((aligned(16))) u16 Vt[64 * 128];    // [d][kv], swizzled
  __shared__ __attribute__((aligned(16))) u16 Pl[4][16 * 128]; // per-wave [q][kv]
  __shared__ __attribute__((aligned(16))) float maskf[Sn];

  const int tid  = threadIdx.x;
  const int wave = tid >> 6;
  const int lane = tid & 63;
  const int ln   = lane & 15;
  const int quad = lane >> 4;
  // XCD-grouping decode: bx = x + 8*(qt + 16*grp), bh = grp*8 + x
  const int bx  = blockIdx.x;
  const int x   = bx & 7;
  const int qt  = (bx >> 3) & 15;
  const int grp = bx >> 7;
  const int bh  = grp * 8 + x;
  const int b   = bh >> 4;
  const int h   = bh & 15;

  const int mt = flags[1];
  for (int i = tid; i < Sn; i += 256) {
    const int idx = b * Sn + i;
    int nz;
    if (mt == 0)      nz = ((const int*)mask)[idx] != 0;
    else if (mt == 1) nz = ((const signed char*)mask)[idx] != 0;
    else if (mt == 2) nz = ((const u16*)mask)[idx] != 0;
    else              nz = ((const unsigned*)mask)[idx] != 0;
    maskf[i] = nz ? -1e9f : 0.0f;
  }

  // Q fragments (B-operand in swapped QK^T: n=lane&15 -> Q-row, k=quad*8+j -> d)
  const size_t qoff = (size_t)(b * Sn + qt * 64 + wave * 16 + ln) * Hn + h * DHn;
  bf16x8 qf0 = *(const bf16x8*)&Qb[qoff + quad * 8];
  bf16x8 qf1 = *(const bf16x8*)&Qb[qoff + 32 + quad * 8];

  float mrun = -INFINITY, lrun = 0.0f;   // this lane's Q-row (ln) running stats
  f32x4 acc[4] = {};

  const int kr = tid >> 1, kh = tid & 1;   // K stage: 2 threads/row (64B each)
  const int vd = tid >> 2, vs = tid & 3;   // V stage: 4 threads/row (64B each)
  char* pw  = (char*)Pl[wave];
  char* KsB = (char*)Ks;
  char* VtB = (char*)Vt;

  const int kwb = kr * 128 + kh * 64;      // K write byte base (unswizzled)
  const int ksw = (kr & 7) << 4;
  const int vwb = vd * 256 + vs * 64;      // V write byte base
  const int vsw = (vd & 7) << 4;
  const int rsw = (ln & 7) << 4;           // read-side swizzle (row&7 == ln&7)
  const int pwb = ln * 256;                // P row base (row = q = ln)
  const int psw = (ln & 7) << 4;

  // r8b: per-lane staging bases + tile-0 prefetch into registers
  const u16* kg = &Kb[(size_t)(b * Sn + kr) * Hn + h * DHn + kh * 32];
  const u16* vg = &Vbt[(size_t)(b * Sn + h * DHn + vd) * Sn + vs * 32];
  bf16x8 kreg[4], vreg[4];
#pragma unroll
  for (int j = 0; j < 4; ++j) kreg[j] = *(const bf16x8*)(kg + j * 8);
#pragma unroll
  for (int j = 0; j < 4; ++j) vreg[j] = *(const bf16x8*)(vg + j * 8);

  for (int t8 = 0; t8 < 8; ++t8) {
    const int kv0 = t8 * 128;
    __syncthreads();  // previous Ks/Vt fully consumed (t8=0: maskf ready too)
#pragma unroll
    for (int j = 0; j < 4; ++j)
      *(bf16x8*)(KsB + ((kwb + j * 16) ^ ksw)) = kreg[j];
#pragma unroll
    for (int j = 0; j < 4; ++j)
      *(bf16x8*)(VtB + ((vwb + j * 16) ^ vsw)) = vreg[j];
    __syncthreads();

    if (t8 < 7) {   // issue next tile's loads; complete under compute below
      const u16* kgn = kg + (size_t)(t8 + 1) * 128 * Hn;
      const u16* vgn = vg + (t8 + 1) * 128;
#pragma unroll
      for (int j = 0; j < 4; ++j) kreg[j] = *(const bf16x8*)(kgn + j * 8);
#pragma unroll
      for (int j = 0; j < 4; ++j) vreg[j] = *(const bf16x8*)(vgn + j * 8);
    }

    // S = K Q^T from LDS: A=K (m=ln -> kv row, k=quad*8+j -> d), B=Q.
    // C[row=quad*4+r -> kv][col=ln -> q].
    f32x4 sc[8];
#pragma unroll
    for (int t = 0; t < 8; ++t) {
      const int rb = (t * 16 + ln) * 128;
      bf16x8 kf0 = *(const bf16x8*)(KsB + ((rb + quad * 16) ^ rsw));
      bf16x8 kf1 = *(const bf16x8*)(KsB + ((rb + 64 + quad * 16) ^ rsw));
      f32x4 z = {};
      z = __builtin_amdgcn_mfma_f32_16x16x32_bf16(kf0, qf0, z, 0, 0, 0);
      z = __builtin_amdgcn_mfma_f32_16x16x32_bf16(kf1, qf1, z, 0, 0, 0);
      sc[t] = z;   // sc[t][r] = S[kv = kv0 + 16t + quad*4 + r][q-row = ln]
    }
    // mask by kv (vectorized: r is 4 consecutive kv)
#pragma unroll
    for (int t = 0; t < 8; ++t) {
      const f32x4 mf4 = *(const f32x4*)&maskf[kv0 + t * 16 + quad * 4];
#pragma unroll
      for (int r = 0; r < 4; ++r) sc[t][r] += mf4[r];
    }

    // in-lane online softmax for Q-row ln: tree max over 32 regs + 2 shfl_xor
    f32x4 mm = sc[0];
#pragma unroll
    for (int t = 1; t < 8; ++t)
#pragma unroll
      for (int r = 0; r < 4; ++r) mm[r] = fmaxf(mm[r], sc[t][r]);
    float vmax = fmaxf(fmaxf(mm[0], mm[1]), fmaxf(mm[2], mm[3]));
    vmax = fmaxf(vmax, __shfl_xor(vmax, 16));
    vmax = fmaxf(vmax, __shfl_xor(vmax, 32));
    const float mnew = fmaxf(mrun, vmax);
    const float al = __expf(mrun - mnew);
    mrun = mnew;
    float ssum = 0.0f;
#pragma unroll
    for (int t = 0; t < 8; ++t)
#pragma unroll
      for (int r = 0; r < 4; ++r) {
        const float p = __expf(sc[t][r] - mnew);
        sc[t][r] = p;
        ssum += p;
      }
    ssum += __shfl_xor(ssum, 16);
    ssum += __shfl_xor(ssum, 32);
    lrun = lrun * al + ssum;

    // P -> LDS [q=ln][kv], packed 8B writes (r consecutive kv), swizzled.
#pragma unroll
    for (int t = 0; t < 8; ++t) {
      u16x4 pk;
#pragma unroll
      for (int r = 0; r < 4; ++r) pk[r] = f2bf(sc[t][r]);
      *(u16x4*)(pw + ((pwb + t * 32 + quad * 8) ^ psw)) = pk;
    }

    // rescale acc: acc rows are q = quad*4+r -> fetch those rows' al
    float alr[4];
#pragma unroll
    for (int r = 0; r < 4; ++r) alr[r] = __shfl(al, quad * 4 + r);
#pragma unroll
    for (int dt = 0; dt < 4; ++dt)
#pragma unroll
      for (int r = 0; r < 4; ++r) acc[dt][r] *= alr[r];

    // PV: A=P (m=ln -> q, k=quad*8+j -> kv), B=V. Same-wave P write->read.
    bf16x8 pa[4];
#pragma unroll
    for (int c = 0; c < 4; ++c)
      pa[c] = *(const bf16x8*)(pw + ((pwb + c * 64 + quad * 16) ^ psw));
#pragma unroll
    for (int dt = 0; dt < 4; ++dt) {
      const int vrb = (dt * 16 + ln) * 256;
#pragma unroll
      for (int c = 0; c < 4; ++c) {
        bf16x8 vb = *(const bf16x8*)(VtB + ((vrb + c * 64 + quad * 16) ^ rsw));
        acc[dt] = __builtin_amdgcn_mfma_f32_16x16x32_bf16(pa[c], vb, acc[dt], 0, 0, 0);
      }
    }
  }

  // acc[dt][r] = O[q = quad*4+r][d = dt*16+ln]; divide by that row's lrun
  float lr[4];
#pragma unroll
  for (int r = 0; r < 4; ++r) lr[r] = __shfl(lrun, quad * 4 + r);
#pragma unroll
  for (int dt = 0; dt < 4; ++dt)
#pragma unroll
    for (int r = 0; r < 4; ++r) {
      const int s = qt * 64 + wave * 16 + quad * 4 + r;
      Ctx[(size_t)(b * Sn + s) * Hn + h * DHn + dt * 16 + ln] = f2bf(acc[dt][r] / lr[r]);
    }
}

extern "C" void kernel_launch(void* const* d_in, const int* in_sizes, int n_in,
                              void* d_out, int out_size, void* d_ws, size_t ws_size,
                              hipStream_t stream) {
  const float* v    = (const float*)d_in[0];
  const float* k    = (const float*)d_in[1];
  const float* q    = (const float*)d_in[2];
  const void*  mask = d_in[3];
  const float* Wq   = (const float*)d_in[4];
  const float* bq   = (const float*)d_in[5];
  const float* Wk   = (const float*)d_in[6];
  const float* bk   = (const float*)d_in[7];
  const float* Wv   = (const float*)d_in[8];
  const float* bv   = (const float*)d_in[9];
  const float* Wm   = (const float*)d_in[10];
  const float* bm   = (const float*)d_in[11];

  // ws layout (56MB + 8B, extents proven safe in round 2/3):
  char* ws = (char*)d_ws;
  u16* qc  = (u16*)(ws);                  // 16MB, consumed by Q-proj -> reused as Vbt
  u16* kc  = (u16*)(ws + (16u << 20));    // 16MB, consumed by K-proj -> reused as Cx
  u16* vc  = (u16*)(ws + (32u << 20));    // 16MB
  u16* Wqc = (u16*)(ws + (48u << 20));    // 2MB each
  u16* Wkc = Wqc + (1u << 20);
  u16* Wvc = Wkc + (1u << 20);
  u16* Wmc = Wvc + (1u << 20);
  int* flags = (int*)(ws + (56u << 20));
  u16* Vbt = qc;
  u16* Cx  = kc;
  u16* Qb  = (u16*)d_out;                 // d_out (32MB f32) hosts Qb+Kb bf16
  u16* Kb  = Qb + (size_t)Mn * Hn;

  sniff_k<<<1, 256, 0, stream>>>(mask, flags);
  convert3<<<3 * 4096, 256, 0, stream>>>(q, k, v, qc, kc, vc);
  convertW<<<4 * 512, 256, 0, stream>>>(Wq, Wk, Wv, Wm, Wqc, Wkc, Wvc, Wmc);

  dim3 blk(256);
  // Fused Q+K projections (independent in/out).
  gemm_qk<<<dim3(Mn / 128, Hn / 128, 2), blk, 0, stream>>>(
      qc, Wqc, bq, Qb, kc, Wkc, bk, Kb);
  dim3 grid(Mn / 128, Hn / 128);
  gemm_bt<2><<<grid, blk, 0, stream>>>(vc, Wvc, bv, Vbt, 1.0f);   // over qc
  attn<<<dim3(Bn * NHn * (Sn / 64)), blk, 0, stream>>>(Qb, Kb, Vbt, mask, flags, Cx); // over kc
  gemm_bt<1><<<grid, blk, 0, stream>>>(Cx, Wmc, bm, d_out, 1.0f);
}

// Round 9
// 330.948 us; speedup vs baseline: 1.5094x; 1.0006x over previous
//
#include <hip/hip_runtime.h>
#include <hip/hip_bf16.h>

// B=8, S=1024, H=1024, NH=16, DH=64. Inputs fp32 (proven r1/r4), output f32
// (proven r4), mask dtype sniffed 4-way. All GEMMs pure bf16 after a convert
// pass; V projection writes per-head-TRANSPOSED Vbt so attention stages V
// coalesced with no scatter.
// r2: attn blockIdx XCD-grouping — K/V L2-hot (FETCH 139MB->25MB, confirmed).
// r3: unpadded XOR-swizzled LDS, 53248B -> 3 blocks/CU; P-barrier dropped.
// r5: softmax reductions off the LDS pipe (attn 129.5 -> 105.7us, confirmed).
// r6: Q+K proj fused; BK=64; staged-source read swizzle.
// r7b+r8b attn: swapped QK^T in-lane softmax + K/V reg-prefetch (93us).
// r9 GEMM: counted-vmcnt 2-phase pipeline (T4). __syncthreads' implicit
//   vmcnt(0) drained the gll queue every K-step (why dbuf/r7a was null).
//   Now: STAGE(t+1); s_waitcnt vmcnt(8) [waits only buf(t)'s 8 oldest];
//   raw s_barrier (asm, "memory"); compute; raw s_barrier. Loads stay in
//   flight across barriers — the m218-proven +38-73% lever.
#define Bn 8
#define Sn 1024
#define Hn 1024
#define NHn 16
#define DHn 64
#define Mn (Bn * Sn)

typedef unsigned short u16;
typedef short bf16x8 __attribute__((ext_vector_type(8)));
typedef unsigned short u16x4 __attribute__((ext_vector_type(4)));
typedef float f32x4 __attribute__((ext_vector_type(4)));

__device__ __forceinline__ u16 f2bf(float x) {
  union { __hip_bfloat16 h; u16 u; } cv;
  cv.h = __float2bfloat16(x);
  return cv.u;
}

__device__ __forceinline__ void async_ld16(void* lds, const void* g) {
  __builtin_amdgcn_global_load_lds(
      (const __attribute__((address_space(1))) void*)g,
      (__attribute__((address_space(3))) void*)lds, 16, 0, 0);
}

// DPP cross-lane helpers kept for reference (unused since r7b).

// ---------------------------------------------------------------------------
// Mask dtype sniffer: flags[1] = 0:i32 1:i8 2:bf16 3:f32 (f32 before bf16).
// ---------------------------------------------------------------------------
__global__ __launch_bounds__(256) void sniff_k(const void* __restrict__ mask,
                                               int* __restrict__ flags) {
  __shared__ int viol;
  if (threadIdx.x == 0) viol = 0;
  __syncthreads();
  const unsigned* mw = (const unsigned*)mask;
  int vb = 0;
#pragma unroll
  for (int j = 0; j < 8; ++j) {
    unsigned v = mw[threadIdx.x * 8 + j];          // first 8192B valid for all dtypes
    if (v > 1u) vb |= 1;
    if ((v & 0xFEFEFEFEu) != 0u) vb |= 2;
    if (!(v == 0u || v == 0x3F800000u)) vb |= 4;
    unsigned h0 = v & 0xFFFFu, h1 = v >> 16;
    if (!((h0 == 0u || h0 == 0x3F80u) && (h1 == 0u || h1 == 0x3F80u))) vb |= 8;
  }
  if (vb) atomicOr(&viol, vb);
  __syncthreads();
  if (threadIdx.x == 0) {
    int mt;
    if (!(viol & 1))      mt = 0;
    else if (!(viol & 2)) mt = 1;
    else if (!(viol & 4)) mt = 3;
    else if (!(viol & 8)) mt = 2;
    else                  mt = 0;
    flags[1] = mt;
  }
}

// fp32 -> bf16: three equal tensors of 8388608 elems, one thread = 8 elems.
__global__ __launch_bounds__(256) void convert3(
    const float* __restrict__ a, const float* __restrict__ b,
    const float* __restrict__ c, u16* __restrict__ da,
    u16* __restrict__ db, u16* __restrict__ dc) {
  const int seg = blockIdx.x >> 12;                 // 4096 blocks per tensor
  const int bid = blockIdx.x & 4095;
  const float* s = seg == 0 ? a : seg == 1 ? b : c;
  u16* d        = seg == 0 ? da : seg == 1 ? db : dc;
  const int i = (bid * 256 + threadIdx.x) * 8;
  f32x4 lo = *(const f32x4*)(s + i);
  f32x4 hi = *(const f32x4*)(s + i + 4);
  bf16x8 o;
#pragma unroll
  for (int j = 0; j < 4; ++j) { o[j] = (short)f2bf(lo[j]); o[4 + j] = (short)f2bf(hi[j]); }
  *(bf16x8*)(d + i) = o;
}

// fp32 -> bf16: four 1048576-elem weights.
__global__ __launch_bounds__(256) void convertW(
    const float* __restrict__ a, const float* __restrict__ b,
    const float* __restrict__ c, const float* __restrict__ e,
    u16* __restrict__ da, u16* __restrict__ db,
    u16* __restrict__ dc, u16* __restrict__ de) {
  const int seg = blockIdx.x >> 9;                  // 512 blocks per tensor
  const int bid = blockIdx.x & 511;
  const float* s = seg == 0 ? a : seg == 1 ? b : seg == 2 ? c : e;
  u16* d        = seg == 0 ? da : seg == 1 ? db : seg == 2 ? dc : de;
  const int i = (bid * 256 + threadIdx.x) * 8;
  f32x4 lo = *(const f32x4*)(s + i);
  f32x4 hi = *(const f32x4*)(s + i + 4);
  bf16x8 o;
#pragma unroll
  for (int j = 0; j < 4; ++j) { o[j] = (short)f2bf(lo[j]); o[4 + j] = (short)f2bf(hi[j]); }
  *(bf16x8*)(d + i) = o;
}

// ---------------------------------------------------------------------------
// O = (X[8192,1024] @ W[1024,1024]^T + bias)*scale, bf16 in, fp32 accum.
// 128x128 tile, BK=64, double-buffered, r9 counted-vmcnt 2-phase:
//   STAGE(0); loop { STAGE(nxt); vmcnt(8) [oldest 8 = cur buf]; s_barrier;
//   compute(cur); s_barrier; }  — prefetch loads stay in flight across the
//   barriers (no vmcnt(0) drain). Race-safety: stage(t+1) overwrites
//   buf[t-1], all reads of which completed before barrier2(t-1) which
//   precedes the stage in program order for every wave.
// Staging: lane loads pre-swizzled global chunk ((l&7)^(row&7)); frag reads
// XOR back -> bank-balanced. OMODE 0: bf16 row-major. 1: f32 row-major.
// 2: bf16 per-head transposed Vbt[(b*1024+col)*1024+s], packed b64 stores.
// ---------------------------------------------------------------------------
template <int OMODE>
__device__ __forceinline__ void gemm_core(
    u16* As, u16* Bs, const u16* __restrict__ X, const u16* __restrict__ W,
    const float* __restrict__ bias, void* __restrict__ O, float scale)
{
  const int tid  = threadIdx.x;
  const int wave = tid >> 6;
  const int lane = tid & 63;
  const int ln   = lane & 15;
  const int quad = lane >> 4;
  const int bxr  = blockIdx.x;                   // 0..63 (M tiles)
  const int m0 = ((bxr & 7) * 8 + (bxr >> 3)) * 128;   // XCD-chunked remap
  const int n0 = blockIdx.y * 128;
  const int wm = (wave & 1) * 64;
  const int wn = (wave >> 1) * 64;
  const int r8 = tid >> 3;                       // staging row within 32-group ×4
  const int cg = ((tid & 7) ^ (r8 & 7)) * 8;     // pre-swizzled global col chunk
  const int rsw = ln & 7;                        // read-side row swizzle bits

  f32x4 acc[4][4] = {};

  auto STAGE = [&](int buf, int k0) {
    char* Ad = (char*)As + buf * 16384 + wave * 1024;   // gll dest: uniform+lane*16
    char* Bd = (char*)Bs + buf * 16384 + wave * 1024;
#pragma unroll
    for (int j = 0; j < 4; ++j) {
      async_ld16(Ad + j * 4096, X + (size_t)(m0 + j * 32 + r8) * 1024 + k0 + cg);
      async_ld16(Bd + j * 4096, W + (size_t)(n0 + j * 32 + r8) * 1024 + k0 + cg);
    }
  };

  STAGE(0, 0);                           // 8 loads in flight
  for (int step = 0; step < 16; ++step) {
    const int cur = step & 1;
    if (step < 15) {
      STAGE(cur ^ 1, (step + 1) * 64);   // +8 -> 16 in flight
      // wait for the OLDEST 8 (= buf[cur]'s loads); next-buf stay in flight
      asm volatile("s_waitcnt vmcnt(8)" ::: "memory");
    } else {
      asm volatile("s_waitcnt vmcnt(0)" ::: "memory");
    }
    asm volatile("s_barrier" ::: "memory");   // all waves' cur-buf loads done
    const char* Ab = (const char*)As + cur * 16384;
    const char* Bb = (const char*)Bs + cur * 16384;
#pragma unroll
    for (int s = 0; s < 2; ++s) {
      const int co = ((s * 4 + quad) ^ rsw) * 16;     // swizzled 16B chunk
      bf16x8 af[4], bfr[4];
#pragma unroll
      for (int t = 0; t < 4; ++t)
        af[t] = *(const bf16x8*)(Ab + (wm + t * 16 + ln) * 128 + co);
#pragma unroll
      for (int t = 0; t < 4; ++t)
        bfr[t] = *(const bf16x8*)(Bb + (wn + t * 16 + ln) * 128 + co);
#pragma unroll
      for (int i = 0; i < 4; ++i)
#pragma unroll
        for (int j = 0; j < 4; ++j)
          acc[i][j] = __builtin_amdgcn_mfma_f32_16x16x32_bf16(af[i], bfr[j], acc[i][j], 0, 0, 0);
    }
    asm volatile("s_barrier" ::: "memory");   // reads of buf[cur] complete
  }

  // C/D: col = lane&15 (+16j), row = quad*4 + r
  if (OMODE == 2) {
    const int bb = m0 >> 10;          // batch (tile never crosses batches)
    const int sb = m0 & 1023;
#pragma unroll
    for (int j = 0; j < 4; ++j) {
      const int col = n0 + wn + j * 16 + ln;
      const float bv = bias[col];
#pragma unroll
      for (int i = 0; i < 4; ++i) {
        const int sl = sb + wm + i * 16 + quad * 4;
        u16x4 pk;
#pragma unroll
        for (int r = 0; r < 4; ++r) pk[r] = f2bf((acc[i][j][r] + bv) * scale);
        *(u16x4*)&((u16*)O)[((size_t)(bb * 1024 + col)) * 1024 + sl] = pk;
      }
    }
  } else {
#pragma unroll
    for (int j = 0; j < 4; ++j) {
      const int col = n0 + wn + j * 16 + ln;
      const float bv = bias[col];
#pragma unroll
      for (int i = 0; i < 4; ++i) {
        const int rowb = m0 + wm + i * 16 + quad * 4;
#pragma unroll
        for (int r = 0; r < 4; ++r) {
          const float val = (acc[i][j][r] + bv) * scale;
          const size_t idx = (size_t)(rowb + r) * 1024 + col;
          if (OMODE == 1) ((float*)O)[idx] = val;
          else            ((u16*)O)[idx]   = f2bf(val);
        }
      }
    }
  }
}

template <int OMODE>
__global__ __launch_bounds__(256, 2) void gemm_bt(
    const u16* __restrict__ X, const u16* __restrict__ W,
    const float* __restrict__ bias, void* __restrict__ O, float scale)
{
  __shared__ __attribute__((aligned(16))) u16 As[2 * 128 * 64];
  __shared__ __attribute__((aligned(16))) u16 Bs[2 * 128 * 64];
  gemm_core<OMODE>(As, Bs, X, W, bias, O, scale);
}

// Fused Q-proj (z=0) + K-proj (z=1): independent inputs/outputs.
__global__ __launch_bounds__(256, 2) void gemm_qk(
    const u16* __restrict__ Xq, const u16* __restrict__ Wq,
    const float* __restrict__ bq, u16* __restrict__ Oq,
    const u16* __restrict__ Xk, const u16* __restrict__ Wk,
    const float* __restrict__ bk, u16* __restrict__ Ok)
{
  __shared__ __attribute__((aligned(16))) u16 As[2 * 128 * 64];
  __shared__ __attribute__((aligned(16))) u16 Bs[2 * 128 * 64];
  const int z = blockIdx.z;
  gemm_core<0>(As, Bs, z ? Xk : Xq, z ? Wk : Wq, z ? bk : bq,
               z ? (void*)Ok : (void*)Oq, z ? 1.0f : 0.125f);
}

// ---------------------------------------------------------------------------
// Flash attention v2 (byte-identical to r8): block = (b,h,64-row Q tile),
// 4 waves x 16 Q-rows, KV-tile 128. r2 XCD swizzle; r3 swizzled LDS (53248B,
// 3 blocks/CU); r7b swapped QK^T + in-lane softmax; r8b K/V reg-prefetch.
// ---------------------------------------------------------------------------
__global__ __launch_bounds__(256, 3) void attn(
    const u16* __restrict__ Qb, const u16* __restrict__ Kb,
    const u16* __restrict__ Vbt, const void* __restrict__ mask,
    const int* __restrict__ flags, u16* __restrict__ Ctx)
{
  __shared__ __attribute__((aligned(16))) u16 Ks[128 * 64];    // [kv][d], swizzled
  __shared__ __attribute__((aligned(16))) u16 Vt[64 * 128];    // [d][kv], swizzled
  __shared__ __attribute__((aligned(16))) u16 Pl[4][16 * 128]; // per-wave [q][kv]
  __shared__ __attribute__((aligned(16))) float maskf[Sn];

  const int tid  = threadIdx.x;
  const int wave = tid >> 6;
  const int lane = tid & 63;
  const int ln   = lane & 15;
  const int quad = lane >> 4;
  // XCD-grouping decode: bx = x + 8*(qt + 16*grp), bh = grp*8 + x
  const int bx  = blockIdx.x;
  const int x   = bx & 7;
  const int qt  = (bx >> 3) & 15;
  const int grp = bx >> 7;
  const int bh  = grp * 8 + x;
  const int b   = bh >> 4;
  const int h   = bh & 15;

  const int mt = flags[1];
  for (int i = tid; i < Sn; i += 256) {
    const int idx = b * Sn + i;
    int nz;
    if (mt == 0)      nz = ((const int*)mask)[idx] != 0;
    else if (mt == 1) nz = ((const signed char*)mask)[idx] != 0;
    else if (mt == 2) nz = ((const u16*)mask)[idx] != 0;
    else              nz = ((const unsigned*)mask)[idx] != 0;
    maskf[i] = nz ? -1e9f : 0.0f;
  }

  // Q fragments (B-operand in swapped QK^T: n=lane&15 -> Q-row, k=quad*8+j -> d)
  const size_t qoff = (size_t)(b * Sn + qt * 64 + wave * 16 + ln) * Hn + h * DHn;
  bf16x8 qf0 = *(const bf16x8*)&Qb[qoff + quad * 8];
  bf16x8 qf1 = *(const bf16x8*)&Qb[qoff + 32 + quad * 8];

  float mrun = -INFINITY, lrun = 0.0f;   // this lane's Q-row (ln) running stats
  f32x4 acc[4] = {};

  const int kr = tid >> 1, kh = tid & 1;   // K stage: 2 threads/row (64B each)
  const int vd = tid >> 2, vs = tid & 3;   // V stage: 4 threads/row (64B each)
  char* pw  = (char*)Pl[wave];
  char* KsB = (char*)Ks;
  char* VtB = (char*)Vt;

  const int kwb = kr * 128 + kh * 64;      // K write byte base (unswizzled)
  const int ksw = (kr & 7) << 4;
  const int vwb = vd * 256 + vs * 64;      // V write byte base
  const int vsw = (vd & 7) << 4;
  const int rsw = (ln & 7) << 4;           // read-side swizzle (row&7 == ln&7)
  const int pwb = ln * 256;                // P row base (row = q = ln)
  const int psw = (ln & 7) << 4;

  // per-lane staging bases + tile-0 prefetch into registers
  const u16* kg = &Kb[(size_t)(b * Sn + kr) * Hn + h * DHn + kh * 32];
  const u16* vg = &Vbt[(size_t)(b * Sn + h * DHn + vd) * Sn + vs * 32];
  bf16x8 kreg[4], vreg[4];
#pragma unroll
  for (int j = 0; j < 4; ++j) kreg[j] = *(const bf16x8*)(kg + j * 8);
#pragma unroll
  for (int j = 0; j < 4; ++j) vreg[j] = *(const bf16x8*)(vg + j * 8);

  for (int t8 = 0; t8 < 8; ++t8) {
    const int kv0 = t8 * 128;
    __syncthreads();  // previous Ks/Vt fully consumed (t8=0: maskf ready too)
#pragma unroll
    for (int j = 0; j < 4; ++j)
      *(bf16x8*)(KsB + ((kwb + j * 16) ^ ksw)) = kreg[j];
#pragma unroll
    for (int j = 0; j < 4; ++j)
      *(bf16x8*)(VtB + ((vwb + j * 16) ^ vsw)) = vreg[j];
    __syncthreads();

    if (t8 < 7) {   // issue next tile's loads; complete under compute below
      const u16* kgn = kg + (size_t)(t8 + 1) * 128 * Hn;
      const u16* vgn = vg + (t8 + 1) * 128;
#pragma unroll
      for (int j = 0; j < 4; ++j) kreg[j] = *(const bf16x8*)(kgn + j * 8);
#pragma unroll
      for (int j = 0; j < 4; ++j) vreg[j] = *(const bf16x8*)(vgn + j * 8);
    }

    // S = K Q^T from LDS: A=K (m=ln -> kv row, k=quad*8+j -> d), B=Q.
    // C[row=quad*4+r -> kv][col=ln -> q].
    f32x4 sc[8];
#pragma unroll
    for (int t = 0; t < 8; ++t) {
      const int rb = (t * 16 + ln) * 128;
      bf16x8 kf0 = *(const bf16x8*)(KsB + ((rb + quad * 16) ^ rsw));
      bf16x8 kf1 = *(const bf16x8*)(KsB + ((rb + 64 + quad * 16) ^ rsw));
      f32x4 z = {};
      z = __builtin_amdgcn_mfma_f32_16x16x32_bf16(kf0, qf0, z, 0, 0, 0);
      z = __builtin_amdgcn_mfma_f32_16x16x32_bf16(kf1, qf1, z, 0, 0, 0);
      sc[t] = z;   // sc[t][r] = S[kv = kv0 + 16t + quad*4 + r][q-row = ln]
    }
    // mask by kv (vectorized: r is 4 consecutive kv)
#pragma unroll
    for (int t = 0; t < 8; ++t) {
      const f32x4 mf4 = *(const f32x4*)&maskf[kv0 + t * 16 + quad * 4];
#pragma unroll
      for (int r = 0; r < 4; ++r) sc[t][r] += mf4[r];
    }

    // in-lane online softmax for Q-row ln: tree max over 32 regs + 2 shfl_xor
    f32x4 mm = sc[0];
#pragma unroll
    for (int t = 1; t < 8; ++t)
#pragma unroll
      for (int r = 0; r < 4; ++r) mm[r] = fmaxf(mm[r], sc[t][r]);
    float vmax = fmaxf(fmaxf(mm[0], mm[1]), fmaxf(mm[2], mm[3]));
    vmax = fmaxf(vmax, __shfl_xor(vmax, 16));
    vmax = fmaxf(vmax, __shfl_xor(vmax, 32));
    const float mnew = fmaxf(mrun, vmax);
    const float al = __expf(mrun - mnew);
    mrun = mnew;
    float ssum = 0.0f;
#pragma unroll
    for (int t = 0; t < 8; ++t)
#pragma unroll
      for (int r = 0; r < 4; ++r) {
        const float p = __expf(sc[t][r] - mnew);
        sc[t][r] = p;
        ssum += p;
      }
    ssum += __shfl_xor(ssum, 16);
    ssum += __shfl_xor(ssum, 32);
    lrun = lrun * al + ssum;

    // P -> LDS [q=ln][kv], packed 8B writes (r consecutive kv), swizzled.
#pragma unroll
    for (int t = 0; t < 8; ++t) {
      u16x4 pk;
#pragma unroll
      for (int r = 0; r < 4; ++r) pk[r] = f2bf(sc[t][r]);
      *(u16x4*)(pw + ((pwb + t * 32 + quad * 8) ^ psw)) = pk;
    }

    // rescale acc: acc rows are q = quad*4+r -> fetch those rows' al
    float alr[4];
#pragma unroll
    for (int r = 0; r < 4; ++r) alr[r] = __shfl(al, quad * 4 + r);
#pragma unroll
    for (int dt = 0; dt < 4; ++dt)
#pragma unroll
      for (int r = 0; r < 4; ++r) acc[dt][r] *= alr[r];

    // PV: A=P (m=ln -> q, k=quad*8+j -> kv), B=V. Same-wave P write->read.
    bf16x8 pa[4];
#pragma unroll
    for (int c = 0; c < 4; ++c)
      pa[c] = *(const bf16x8*)(pw + ((pwb + c * 64 + quad * 16) ^ psw));
#pragma unroll
    for (int dt = 0; dt < 4; ++dt) {
      const int vrb = (dt * 16 + ln) * 256;
#pragma unroll
      for (int c = 0; c < 4; ++c) {
        bf16x8 vb = *(const bf16x8*)(VtB + ((vrb + c * 64 + quad * 16) ^ rsw));
        acc[dt] = __builtin_amdgcn_mfma_f32_16x16x32_bf16(pa[c], vb, acc[dt], 0, 0, 0);
      }
    }
  }

  // acc[dt][r] = O[q = quad*4+r][d = dt*16+ln]; divide by that row's lrun
  float lr[4];
#pragma unroll
  for (int r = 0; r < 4; ++r) lr[r] = __shfl(lrun, quad * 4 + r);
#pragma unroll
  for (int dt = 0; dt < 4; ++dt)
#pragma unroll
    for (int r = 0; r < 4; ++r) {
      const int s = qt * 64 + wave * 16 + quad * 4 + r;
      Ctx[(size_t)(b * Sn + s) * Hn + h * DHn + dt * 16 + ln] = f2bf(acc[dt][r] / lr[r]);
    }
}

extern "C" void kernel_launch(void* const* d_in, const int* in_sizes, int n_in,
                              void* d_out, int out_size, void* d_ws, size_t ws_size,
                              hipStream_t stream) {
  const float* v    = (const float*)d_in[0];
  const float* k    = (const float*)d_in[1];
  const float* q    = (const float*)d_in[2];
  const void*  mask = d_in[3];
  const float* Wq   = (const float*)d_in[4];
  const float* bq   = (const float*)d_in[5];
  const float* Wk   = (const float*)d_in[6];
  const float* bk   = (const float*)d_in[7];
  const float* Wv   = (const float*)d_in[8];
  const float* bv   = (const float*)d_in[9];
  const float* Wm   = (const float*)d_in[10];
  const float* bm   = (const float*)d_in[11];

  // ws layout (56MB + 8B, extents proven safe in round 2/3):
  char* ws = (char*)d_ws;
  u16* qc  = (u16*)(ws);                  // 16MB, consumed by Q-proj -> reused as Vbt
  u16* kc  = (u16*)(ws + (16u << 20));    // 16MB, consumed by K-proj -> reused as Cx
  u16* vc  = (u16*)(ws + (32u << 20));    // 16MB
  u16* Wqc = (u16*)(ws + (48u << 20));    // 2MB each
  u16* Wkc = Wqc + (1u << 20);
  u16* Wvc = Wkc + (1u << 20);
  u16* Wmc = Wvc + (1u << 20);
  int* flags = (int*)(ws + (56u << 20));
  u16* Vbt = qc;
  u16* Cx  = kc;
  u16* Qb  = (u16*)d_out;                 // d_out (32MB f32) hosts Qb+Kb bf16
  u16* Kb  = Qb + (size_t)Mn * Hn;

  sniff_k<<<1, 256, 0, stream>>>(mask, flags);
  convert3<<<3 * 4096, 256, 0, stream>>>(q, k, v, qc, kc, vc);
  convertW<<<4 * 512, 256, 0, stream>>>(Wq, Wk, Wv, Wm, Wqc, Wkc, Wvc, Wmc);

  dim3 blk(256);
  // Fused Q+K projections (independent in/out).
  gemm_qk<<<dim3(Mn / 128, Hn / 128, 2), blk, 0, stream>>>(
      qc, Wqc, bq, Qb, kc, Wkc, bk, Kb);
  dim3 grid(Mn / 128, Hn / 128);
  gemm_bt<2><<<grid, blk, 0, stream>>>(vc, Wvc, bv, Vbt, 1.0f);   // over qc
  attn<<<dim3(Bn * NHn * (Sn / 64)), blk, 0, stream>>>(Qb, Kb, Vbt, mask, flags, Cx); // over kc
  gemm_bt<1><<<grid, blk, 0, stream>>>(Cx, Wmc, bm, d_out, 1.0f);
}

// Round 10
// 313.574 us; speedup vs baseline: 1.5930x; 1.0554x over previous
//
#include <hip/hip_runtime.h>
#include <hip/hip_bf16.h>

// B=8, S=1024, H=1024, NH=16, DH=64. Inputs fp32 (proven r1/r4), output f32
// (proven r4), mask dtype sniffed 4-way. All GEMMs pure bf16 after a convert
// pass; V projection writes per-head-TRANSPOSED Vbt so attention stages V
// coalesced with no scatter.
// r2: attn blockIdx XCD-grouping — K/V L2-hot (FETCH 139MB->25MB, confirmed).
// r3: unpadded XOR-swizzled LDS; r5: DPP/in-lane softmax off the LDS pipe
// (129.5->105.7us); r7b: swapped QK^T in-lane softmax; r8b: K/V reg-prefetch
// (->93us). r9 GEMM: counted-vmcnt 2-phase (kept; GEMM frozen after 6 nulls).
// r10 attn: 32 Q-rows/wave (two 16-row halves). One kf/vb LDS read feeds both
// halves' MFMAs; staging, mask reads, barriers amortize 2x. LDS ops per FLOP
// -40%. Pl widens to 32 rows/wave -> LDS 69632B, 2 blocks/CU; grid halves to
// 1024 blocks (8 qt per bh, XCD decode adjusted).
#define Bn 8
#define Sn 1024
#define Hn 1024
#define NHn 16
#define DHn 64
#define Mn (Bn * Sn)

typedef unsigned short u16;
typedef short bf16x8 __attribute__((ext_vector_type(8)));
typedef unsigned short u16x4 __attribute__((ext_vector_type(4)));
typedef float f32x4 __attribute__((ext_vector_type(4)));

__device__ __forceinline__ u16 f2bf(float x) {
  union { __hip_bfloat16 h; u16 u; } cv;
  cv.h = __float2bfloat16(x);
  return cv.u;
}

__device__ __forceinline__ void async_ld16(void* lds, const void* g) {
  __builtin_amdgcn_global_load_lds(
      (const __attribute__((address_space(1))) void*)g,
      (__attribute__((address_space(3))) void*)lds, 16, 0, 0);
}

// ---------------------------------------------------------------------------
// Mask dtype sniffer: flags[1] = 0:i32 1:i8 2:bf16 3:f32 (f32 before bf16).
// ---------------------------------------------------------------------------
__global__ __launch_bounds__(256) void sniff_k(const void* __restrict__ mask,
                                               int* __restrict__ flags) {
  __shared__ int viol;
  if (threadIdx.x == 0) viol = 0;
  __syncthreads();
  const unsigned* mw = (const unsigned*)mask;
  int vb = 0;
#pragma unroll
  for (int j = 0; j < 8; ++j) {
    unsigned v = mw[threadIdx.x * 8 + j];          // first 8192B valid for all dtypes
    if (v > 1u) vb |= 1;
    if ((v & 0xFEFEFEFEu) != 0u) vb |= 2;
    if (!(v == 0u || v == 0x3F800000u)) vb |= 4;
    unsigned h0 = v & 0xFFFFu, h1 = v >> 16;
    if (!((h0 == 0u || h0 == 0x3F80u) && (h1 == 0u || h1 == 0x3F80u))) vb |= 8;
  }
  if (vb) atomicOr(&viol, vb);
  __syncthreads();
  if (threadIdx.x == 0) {
    int mt;
    if (!(viol & 1))      mt = 0;
    else if (!(viol & 2)) mt = 1;
    else if (!(viol & 4)) mt = 3;
    else if (!(viol & 8)) mt = 2;
    else                  mt = 0;
    flags[1] = mt;
  }
}

// fp32 -> bf16: three equal tensors of 8388608 elems, one thread = 8 elems.
__global__ __launch_bounds__(256) void convert3(
    const float* __restrict__ a, const float* __restrict__ b,
    const float* __restrict__ c, u16* __restrict__ da,
    u16* __restrict__ db, u16* __restrict__ dc) {
  const int seg = blockIdx.x >> 12;                 // 4096 blocks per tensor
  const int bid = blockIdx.x & 4095;
  const float* s = seg == 0 ? a : seg == 1 ? b : c;
  u16* d        = seg == 0 ? da : seg == 1 ? db : dc;
  const int i = (bid * 256 + threadIdx.x) * 8;
  f32x4 lo = *(const f32x4*)(s + i);
  f32x4 hi = *(const f32x4*)(s + i + 4);
  bf16x8 o;
#pragma unroll
  for (int j = 0; j < 4; ++j) { o[j] = (short)f2bf(lo[j]); o[4 + j] = (short)f2bf(hi[j]); }
  *(bf16x8*)(d + i) = o;
}

// fp32 -> bf16: four 1048576-elem weights.
__global__ __launch_bounds__(256) void convertW(
    const float* __restrict__ a, const float* __restrict__ b,
    const float* __restrict__ c, const float* __restrict__ e,
    u16* __restrict__ da, u16* __restrict__ db,
    u16* __restrict__ dc, u16* __restrict__ de) {
  const int seg = blockIdx.x >> 9;                  // 512 blocks per tensor
  const int bid = blockIdx.x & 511;
  const float* s = seg == 0 ? a : seg == 1 ? b : seg == 2 ? c : e;
  u16* d        = seg == 0 ? da : seg == 1 ? db : seg == 2 ? dc : de;
  const int i = (bid * 256 + threadIdx.x) * 8;
  f32x4 lo = *(const f32x4*)(s + i);
  f32x4 hi = *(const f32x4*)(s + i + 4);
  bf16x8 o;
#pragma unroll
  for (int j = 0; j < 4; ++j) { o[j] = (short)f2bf(lo[j]); o[4 + j] = (short)f2bf(hi[j]); }
  *(bf16x8*)(d + i) = o;
}

// ---------------------------------------------------------------------------
// O = (X[8192,1024] @ W[1024,1024]^T + bias)*scale, bf16 in, fp32 accum.
// 128x128 tile, BK=64, double-buffered, counted-vmcnt 2-phase (r9, frozen).
// ---------------------------------------------------------------------------
template <int OMODE>
__device__ __forceinline__ void gemm_core(
    u16* As, u16* Bs, const u16* __restrict__ X, const u16* __restrict__ W,
    const float* __restrict__ bias, void* __restrict__ O, float scale)
{
  const int tid  = threadIdx.x;
  const int wave = tid >> 6;
  const int lane = tid & 63;
  const int ln   = lane & 15;
  const int quad = lane >> 4;
  const int bxr  = blockIdx.x;                   // 0..63 (M tiles)
  const int m0 = ((bxr & 7) * 8 + (bxr >> 3)) * 128;   // XCD-chunked remap
  const int n0 = blockIdx.y * 128;
  const int wm = (wave & 1) * 64;
  const int wn = (wave >> 1) * 64;
  const int r8 = tid >> 3;                       // staging row within 32-group ×4
  const int cg = ((tid & 7) ^ (r8 & 7)) * 8;     // pre-swizzled global col chunk
  const int rsw = ln & 7;                        // read-side row swizzle bits

  f32x4 acc[4][4] = {};

  auto STAGE = [&](int buf, int k0) {
    char* Ad = (char*)As + buf * 16384 + wave * 1024;   // gll dest: uniform+lane*16
    char* Bd = (char*)Bs + buf * 16384 + wave * 1024;
#pragma unroll
    for (int j = 0; j < 4; ++j) {
      async_ld16(Ad + j * 4096, X + (size_t)(m0 + j * 32 + r8) * 1024 + k0 + cg);
      async_ld16(Bd + j * 4096, W + (size_t)(n0 + j * 32 + r8) * 1024 + k0 + cg);
    }
  };

  STAGE(0, 0);                           // 8 loads in flight
  for (int step = 0; step < 16; ++step) {
    const int cur = step & 1;
    if (step < 15) {
      STAGE(cur ^ 1, (step + 1) * 64);   // +8 -> 16 in flight
      asm volatile("s_waitcnt vmcnt(8)" ::: "memory");
    } else {
      asm volatile("s_waitcnt vmcnt(0)" ::: "memory");
    }
    asm volatile("s_barrier" ::: "memory");   // all waves' cur-buf loads done
    const char* Ab = (const char*)As + cur * 16384;
    const char* Bb = (const char*)Bs + cur * 16384;
#pragma unroll
    for (int s = 0; s < 2; ++s) {
      const int co = ((s * 4 + quad) ^ rsw) * 16;     // swizzled 16B chunk
      bf16x8 af[4], bfr[4];
#pragma unroll
      for (int t = 0; t < 4; ++t)
        af[t] = *(const bf16x8*)(Ab + (wm + t * 16 + ln) * 128 + co);
#pragma unroll
      for (int t = 0; t < 4; ++t)
        bfr[t] = *(const bf16x8*)(Bb + (wn + t * 16 + ln) * 128 + co);
#pragma unroll
      for (int i = 0; i < 4; ++i)
#pragma unroll
        for (int j = 0; j < 4; ++j)
          acc[i][j] = __builtin_amdgcn_mfma_f32_16x16x32_bf16(af[i], bfr[j], acc[i][j], 0, 0, 0);
    }
    asm volatile("s_barrier" ::: "memory");   // reads of buf[cur] complete
  }

  // C/D: col = lane&15 (+16j), row = quad*4 + r
  if (OMODE == 2) {
    const int bb = m0 >> 10;          // batch (tile never crosses batches)
    const int sb = m0 & 1023;
#pragma unroll
    for (int j = 0; j < 4; ++j) {
      const int col = n0 + wn + j * 16 + ln;
      const float bv = bias[col];
#pragma unroll
      for (int i = 0; i < 4; ++i) {
        const int sl = sb + wm + i * 16 + quad * 4;
        u16x4 pk;
#pragma unroll
        for (int r = 0; r < 4; ++r) pk[r] = f2bf((acc[i][j][r] + bv) * scale);
        *(u16x4*)&((u16*)O)[((size_t)(bb * 1024 + col)) * 1024 + sl] = pk;
      }
    }
  } else {
#pragma unroll
    for (int j = 0; j < 4; ++j) {
      const int col = n0 + wn + j * 16 + ln;
      const float bv = bias[col];
#pragma unroll
      for (int i = 0; i < 4; ++i) {
        const int rowb = m0 + wm + i * 16 + quad * 4;
#pragma unroll
        for (int r = 0; r < 4; ++r) {
          const float val = (acc[i][j][r] + bv) * scale;
          const size_t idx = (size_t)(rowb + r) * 1024 + col;
          if (OMODE == 1) ((float*)O)[idx] = val;
          else            ((u16*)O)[idx]   = f2bf(val);
        }
      }
    }
  }
}

template <int OMODE>
__global__ __launch_bounds__(256, 2) void gemm_bt(
    const u16* __restrict__ X, const u16* __restrict__ W,
    const float* __restrict__ bias, void* __restrict__ O, float scale)
{
  __shared__ __attribute__((aligned(16))) u16 As[2 * 128 * 64];
  __shared__ __attribute__((aligned(16))) u16 Bs[2 * 128 * 64];
  gemm_core<OMODE>(As, Bs, X, W, bias, O, scale);
}

// Fused Q-proj (z=0) + K-proj (z=1): independent inputs/outputs.
__global__ __launch_bounds__(256, 2) void gemm_qk(
    const u16* __restrict__ Xq, const u16* __restrict__ Wq,
    const float* __restrict__ bq, u16* __restrict__ Oq,
    const u16* __restrict__ Xk, const u16* __restrict__ Wk,
    const float* __restrict__ bk, u16* __restrict__ Ok)
{
  __shared__ __attribute__((aligned(16))) u16 As[2 * 128 * 64];
  __shared__ __attribute__((aligned(16))) u16 Bs[2 * 128 * 64];
  const int z = blockIdx.z;
  gemm_core<0>(As, Bs, z ? Xk : Xq, z ? Wk : Wq, z ? bk : bq,
               z ? (void*)Ok : (void*)Oq, z ? 1.0f : 0.125f);
}

// ---------------------------------------------------------------------------
// Flash attention v2: block = (b,h,128-row Q tile), 4 waves x 32 Q-rows
// (two 16-row halves A/B), KV-tile 128 (8 iterations). One kf/vb LDS read
// feeds both halves' MFMAs; staging/mask/barriers amortized 2x. r2 XCD
// swizzle (8 qt per bh); swapped QK^T + in-lane softmax per half; K/V
// reg-prefetch one tile ahead. LDS 69632B -> 2 blocks/CU.
// ---------------------------------------------------------------------------
__global__ __launch_bounds__(256, 2) void attn(
    const u16* __restrict__ Qb, const u16* __restrict__ Kb,
    const u16* __restrict__ Vbt, const void* __restrict__ mask,
    const int* __restrict__ flags, u16* __restrict__ Ctx)
{
  __shared__ __attribute__((aligned(16))) u16 Ks[128 * 64];    // [kv][d], swizzled
  __shared__ __attribute__((aligned(16))) u16 Vt[64 * 128];    // [d][kv], swizzled
  __shared__ __attribute__((aligned(16))) u16 Pl[4][32 * 128]; // per-wave [q][kv]
  __shared__ __attribute__((aligned(16))) float maskf[Sn];

  const int tid  = threadIdx.x;
  const int wave = tid >> 6;
  const int lane = tid & 63;
  const int ln   = lane & 15;
  const int quad = lane >> 4;
  // XCD-grouping decode: bx = x + 8*(qt + 8*grp), bh = grp*8 + x
  const int bx  = blockIdx.x;
  const int x   = bx & 7;
  const int qt  = (bx >> 3) & 7;
  const int grp = bx >> 6;
  const int bh  = grp * 8 + x;
  const int b   = bh >> 4;
  const int h   = bh & 15;

  const int mt = flags[1];
  for (int i = tid; i < Sn; i += 256) {
    const int idx = b * Sn + i;
    int nz;
    if (mt == 0)      nz = ((const int*)mask)[idx] != 0;
    else if (mt == 1) nz = ((const signed char*)mask)[idx] != 0;
    else if (mt == 2) nz = ((const u16*)mask)[idx] != 0;
    else              nz = ((const unsigned*)mask)[idx] != 0;
    maskf[i] = nz ? -1e9f : 0.0f;
  }

  // Q fragments, two 16-row halves (B-operand: n=ln -> Q-row, k=quad*8+j -> d)
  const size_t qoffA = (size_t)(b * Sn + qt * 128 + wave * 16 + ln) * Hn + h * DHn;
  const size_t qoffB = qoffA + (size_t)64 * Hn;
  bf16x8 qfA0 = *(const bf16x8*)&Qb[qoffA + quad * 8];
  bf16x8 qfA1 = *(const bf16x8*)&Qb[qoffA + 32 + quad * 8];
  bf16x8 qfB0 = *(const bf16x8*)&Qb[qoffB + quad * 8];
  bf16x8 qfB1 = *(const bf16x8*)&Qb[qoffB + 32 + quad * 8];

  float mrunA = -INFINITY, lrunA = 0.0f;
  float mrunB = -INFINITY, lrunB = 0.0f;
  f32x4 accA[4] = {}, accB[4] = {};

  const int kr = tid >> 1, kh = tid & 1;   // K stage: 2 threads/row (64B each)
  const int vd = tid >> 2, vs = tid & 3;   // V stage: 4 threads/row (64B each)
  char* pw  = (char*)Pl[wave];
  char* KsB = (char*)Ks;
  char* VtB = (char*)Vt;

  const int kwb = kr * 128 + kh * 64;      // K write byte base (unswizzled)
  const int ksw = (kr & 7) << 4;
  const int vwb = vd * 256 + vs * 64;      // V write byte base
  const int vsw = (vd & 7) << 4;
  const int rsw = (ln & 7) << 4;           // read-side swizzle (row&7 == ln&7)
  const int pwbA = ln * 256;               // P row bases (rows ln and 16+ln)
  const int pwbB = (16 + ln) * 256;
  const int psw = (ln & 7) << 4;           // (16+ln)&7 == ln&7

  // per-lane staging bases + tile-0 prefetch into registers
  const u16* kg = &Kb[(size_t)(b * Sn + kr) * Hn + h * DHn + kh * 32];
  const u16* vg = &Vbt[(size_t)(b * Sn + h * DHn + vd) * Sn + vs * 32];
  bf16x8 kreg[4], vreg[4];
#pragma unroll
  for (int j = 0; j < 4; ++j) kreg[j] = *(const bf16x8*)(kg + j * 8);
#pragma unroll
  for (int j = 0; j < 4; ++j) vreg[j] = *(const bf16x8*)(vg + j * 8);

  for (int t8 = 0; t8 < 8; ++t8) {
    const int kv0 = t8 * 128;
    __syncthreads();  // previous Ks/Vt fully consumed (t8=0: maskf ready too)
#pragma unroll
    for (int j = 0; j < 4; ++j)
      *(bf16x8*)(KsB + ((kwb + j * 16) ^ ksw)) = kreg[j];
#pragma unroll
    for (int j = 0; j < 4; ++j)
      *(bf16x8*)(VtB + ((vwb + j * 16) ^ vsw)) = vreg[j];
    __syncthreads();

    if (t8 < 7) {   // issue next tile's loads; complete under compute below
      const u16* kgn = kg + (size_t)(t8 + 1) * 128 * Hn;
      const u16* vgn = vg + (t8 + 1) * 128;
#pragma unroll
      for (int j = 0; j < 4; ++j) kreg[j] = *(const bf16x8*)(kgn + j * 8);
#pragma unroll
      for (int j = 0; j < 4; ++j) vreg[j] = *(const bf16x8*)(vgn + j * 8);
    }

    // S = K Q^T: one kf pair feeds BOTH halves. C[kv=quad*4+r][q=ln].
    f32x4 scA[8], scB[8];
#pragma unroll
    for (int t = 0; t < 8; ++t) {
      const int rb = (t * 16 + ln) * 128;
      bf16x8 kf0 = *(const bf16x8*)(KsB + ((rb + quad * 16) ^ rsw));
      bf16x8 kf1 = *(const bf16x8*)(KsB + ((rb + 64 + quad * 16) ^ rsw));
      f32x4 zA = {}, zB = {};
      zA = __builtin_amdgcn_mfma_f32_16x16x32_bf16(kf0, qfA0, zA, 0, 0, 0);
      zA = __builtin_amdgcn_mfma_f32_16x16x32_bf16(kf1, qfA1, zA, 0, 0, 0);
      zB = __builtin_amdgcn_mfma_f32_16x16x32_bf16(kf0, qfB0, zB, 0, 0, 0);
      zB = __builtin_amdgcn_mfma_f32_16x16x32_bf16(kf1, qfB1, zB, 0, 0, 0);
      scA[t] = zA;
      scB[t] = zB;
    }
    // mask by kv, shared by both halves
#pragma unroll
    for (int t = 0; t < 8; ++t) {
      const f32x4 mf4 = *(const f32x4*)&maskf[kv0 + t * 16 + quad * 4];
#pragma unroll
      for (int r = 0; r < 4; ++r) { scA[t][r] += mf4[r]; scB[t][r] += mf4[r]; }
    }

    // in-lane online softmax per half (VALU; 2 shfl_xor per reduce)
    float alA, alB;
    {
      f32x4 mm = scA[0];
#pragma unroll
      for (int t = 1; t < 8; ++t)
#pragma unroll
        for (int r = 0; r < 4; ++r) mm[r] = fmaxf(mm[r], scA[t][r]);
      float vmax = fmaxf(fmaxf(mm[0], mm[1]), fmaxf(mm[2], mm[3]));
      vmax = fmaxf(vmax, __shfl_xor(vmax, 16));
      vmax = fmaxf(vmax, __shfl_xor(vmax, 32));
      const float mnew = fmaxf(mrunA, vmax);
      alA = __expf(mrunA - mnew);
      mrunA = mnew;
      float ssum = 0.0f;
#pragma unroll
      for (int t = 0; t < 8; ++t)
#pragma unroll
        for (int r = 0; r < 4; ++r) {
          const float p = __expf(scA[t][r] - mnew);
          scA[t][r] = p;
          ssum += p;
        }
      ssum += __shfl_xor(ssum, 16);
      ssum += __shfl_xor(ssum, 32);
      lrunA = lrunA * alA + ssum;
    }
    {
      f32x4 mm = scB[0];
#pragma unroll
      for (int t = 1; t < 8; ++t)
#pragma unroll
        for (int r = 0; r < 4; ++r) mm[r] = fmaxf(mm[r], scB[t][r]);
      float vmax = fmaxf(fmaxf(mm[0], mm[1]), fmaxf(mm[2], mm[3]));
      vmax = fmaxf(vmax, __shfl_xor(vmax, 16));
      vmax = fmaxf(vmax, __shfl_xor(vmax, 32));
      const float mnew = fmaxf(mrunB, vmax);
      alB = __expf(mrunB - mnew);
      mrunB = mnew;
      float ssum = 0.0f;
#pragma unroll
      for (int t = 0; t < 8; ++t)
#pragma unroll
        for (int r = 0; r < 4; ++r) {
          const float p = __expf(scB[t][r] - mnew);
          scB[t][r] = p;
          ssum += p;
        }
      ssum += __shfl_xor(ssum, 16);
      ssum += __shfl_xor(ssum, 32);
      lrunB = lrunB * alB + ssum;
    }

    // P -> LDS [q][kv], packed 8B writes, both halves
#pragma unroll
    for (int t = 0; t < 8; ++t) {
      u16x4 pkA, pkB;
#pragma unroll
      for (int r = 0; r < 4; ++r) { pkA[r] = f2bf(scA[t][r]); pkB[r] = f2bf(scB[t][r]); }
      *(u16x4*)(pw + ((pwbA + t * 32 + quad * 8) ^ psw)) = pkA;
      *(u16x4*)(pw + ((pwbB + t * 32 + quad * 8) ^ psw)) = pkB;
    }

    // rescale acc: acc rows are q = quad*4+r
    float alrA[4], alrB[4];
#pragma unroll
    for (int r = 0; r < 4; ++r) {
      alrA[r] = __shfl(alA, quad * 4 + r);
      alrB[r] = __shfl(alB, quad * 4 + r);
    }
#pragma unroll
    for (int dt = 0; dt < 4; ++dt)
#pragma unroll
      for (int r = 0; r < 4; ++r) { accA[dt][r] *= alrA[r]; accB[dt][r] *= alrB[r]; }

    // PV: one vb read feeds both halves. Same-wave P write->read.
    bf16x8 paA[4], paB[4];
#pragma unroll
    for (int c = 0; c < 4; ++c) {
      paA[c] = *(const bf16x8*)(pw + ((pwbA + c * 64 + quad * 16) ^ psw));
      paB[c] = *(const bf16x8*)(pw + ((pwbB + c * 64 + quad * 16) ^ psw));
    }
#pragma unroll
    for (int dt = 0; dt < 4; ++dt) {
      const int vrb = (dt * 16 + ln) * 256;
#pragma unroll
      for (int c = 0; c < 4; ++c) {
        bf16x8 vb = *(const bf16x8*)(VtB + ((vrb + c * 64 + quad * 16) ^ rsw));
        accA[dt] = __builtin_amdgcn_mfma_f32_16x16x32_bf16(paA[c], vb, accA[dt], 0, 0, 0);
        accB[dt] = __builtin_amdgcn_mfma_f32_16x16x32_bf16(paB[c], vb, accB[dt], 0, 0, 0);
      }
    }
  }

  // acc[dt][r] = O[q = quad*4+r][d = dt*16+ln]; divide by that row's lrun
  float lrA[4], lrB[4];
#pragma unroll
  for (int r = 0; r < 4; ++r) {
    lrA[r] = __shfl(lrunA, quad * 4 + r);
    lrB[r] = __shfl(lrunB, quad * 4 + r);
  }
#pragma unroll
  for (int dt = 0; dt < 4; ++dt)
#pragma unroll
    for (int r = 0; r < 4; ++r) {
      const int sA = qt * 128 + wave * 16 + quad * 4 + r;
      Ctx[(size_t)(b * Sn + sA) * Hn + h * DHn + dt * 16 + ln] = f2bf(accA[dt][r] / lrA[r]);
      Ctx[(size_t)(b * Sn + sA + 64) * Hn + h * DHn + dt * 16 + ln] = f2bf(accB[dt][r] / lrB[r]);
    }
}

extern "C" void kernel_launch(void* const* d_in, const int* in_sizes, int n_in,
                              void* d_out, int out_size, void* d_ws, size_t ws_size,
                              hipStream_t stream) {
  const float* v    = (const float*)d_in[0];
  const float* k    = (const float*)d_in[1];
  const float* q    = (const float*)d_in[2];
  const void*  mask = d_in[3];
  const float* Wq   = (const float*)d_in[4];
  const float* bq   = (const float*)d_in[5];
  const float* Wk   = (const float*)d_in[6];
  const float* bk   = (const float*)d_in[7];
  const float* Wv   = (const float*)d_in[8];
  const float* bv   = (const float*)d_in[9];
  const float* Wm   = (const float*)d_in[10];
  const float* bm   = (const float*)d_in[11];

  // ws layout (56MB + 8B, extents proven safe in round 2/3):
  char* ws = (char*)d_ws;
  u16* qc  = (u16*)(ws);                  // 16MB, consumed by Q-proj -> reused as Vbt
  u16* kc  = (u16*)(ws + (16u << 20));    // 16MB, consumed by K-proj -> reused as Cx
  u16* vc  = (u16*)(ws + (32u << 20));    // 16MB
  u16* Wqc = (u16*)(ws + (48u << 20));    // 2MB each
  u16* Wkc = Wqc + (1u << 20);
  u16* Wvc = Wkc + (1u << 20);
  u16* Wmc = Wvc + (1u << 20);
  int* flags = (int*)(ws + (56u << 20));
  u16* Vbt = qc;
  u16* Cx  = kc;
  u16* Qb  = (u16*)d_out;                 // d_out (32MB f32) hosts Qb+Kb bf16
  u16* Kb  = Qb + (size_t)Mn * Hn;

  sniff_k<<<1, 256, 0, stream>>>(mask, flags);
  convert3<<<3 * 4096, 256, 0, stream>>>(q, k, v, qc, kc, vc);
  convertW<<<4 * 512, 256, 0, stream>>>(Wq, Wk, Wv, Wm, Wqc, Wkc, Wvc, Wmc);

  dim3 blk(256);
  // Fused Q+K projections (independent in/out).
  gemm_qk<<<dim3(Mn / 128, Hn / 128, 2), blk, 0, stream>>>(
      qc, Wqc, bq, Qb, kc, Wkc, bk, Kb);
  dim3 grid(Mn / 128, Hn / 128);
  gemm_bt<2><<<grid, blk, 0, stream>>>(vc, Wvc, bv, Vbt, 1.0f);   // over qc
  attn<<<dim3(Bn * NHn * (Sn / 128)), blk, 0, stream>>>(Qb, Kb, Vbt, mask, flags, Cx); // over kc
  gemm_bt<1><<<grid, blk, 0, stream>>>(Cx, Wmc, bm, d_out, 1.0f);
}